// Round 4
// baseline (3725.140 us; speedup 1.0000x reference)
//
#include <hip/hip_runtime.h>
#include <hip/hip_bf16.h>
#include <cstdint>
#include <cstddef>

#define DEV __device__ __forceinline__

// ---------------- problem constants ----------------
constexpr int BB    = 32;
constexpr int SEQ   = 1024;
constexpr int HID   = 1152;
constexpr int HEADS = 12;
constexpr int KVH   = 4;
constexpr int HD    = 96;
constexpr int KVC   = 384;   // KVH*HD
constexpr int MLPD  = 4608;
constexpr int ROWS  = BB * SEQ;          // 32768
constexpr int MODW  = 6 * HID;           // 6912

typedef __attribute__((ext_vector_type(8))) short short8;
typedef __attribute__((ext_vector_type(4))) float f32x4;

// ---------------- helpers ----------------
DEV float bfu2f(unsigned short u) {
    unsigned v = ((unsigned)u) << 16;
    return __builtin_bit_cast(float, v);
}
DEV unsigned short f2bf16u(float f) {
    unsigned u = __builtin_bit_cast(unsigned, f);
    u += 0x7FFFu + ((u >> 16) & 1u);   // RNE
    return (unsigned short)(u >> 16);
}
DEV unsigned pack2(float a, float b) {
    return (unsigned)f2bf16u(a) | ((unsigned)f2bf16u(b) << 16);
}
DEV float gelu_tanh(float x) {
    float x3 = x * x * x;
    float t = tanhf(0.7978845608028654f * (x + 0.044715f * x3));
    return 0.5f * x * (1.f + t);
}

// async global->LDS, 16B per lane. LDS dest must be wave-uniform base (+lane*16).
DEV void gload16(const void* g, void* l) {
    __builtin_amdgcn_global_load_lds(
        (const __attribute__((address_space(1))) unsigned int*)g,
        (__attribute__((address_space(3))) unsigned int*)l,
        16, 0, 0);
}

// block reduce of two floats, blockDim.x == 256
DEV void block_reduce2(float& a, float& b) {
    #pragma unroll
    for (int off = 32; off > 0; off >>= 1) {
        a += __shfl_down(a, off, 64);
        b += __shfl_down(b, off, 64);
    }
    __shared__ float sa[4], sb[4];
    int w = threadIdx.x >> 6;
    if ((threadIdx.x & 63) == 0) { sa[w] = a; sb[w] = b; }
    __syncthreads();
    a = sa[0] + sa[1] + sa[2] + sa[3];
    b = sb[0] + sb[1] + sb[2] + sb[3];
    __syncthreads();
}

// ---------------- weight transpose + bf16 convert ----------------
__global__ void k_transpose_bf16(const float* __restrict__ in,
                                 unsigned short* __restrict__ out, int K, int N) {
    __shared__ float tile[32][33];
    int kb = blockIdx.x * 32;
    int nb = blockIdx.y * 32;
    int tx = threadIdx.x, ty = threadIdx.y;   // (32, 8)
    #pragma unroll
    for (int j = 0; j < 4; j++) {
        int k = kb + ty + j * 8;
        tile[ty + j * 8][tx] = (k < K && nb + tx < N) ? in[(size_t)k * N + nb + tx] : 0.f;
    }
    __syncthreads();
    #pragma unroll
    for (int j = 0; j < 4; j++) {
        int n = nb + ty + j * 8;
        if (n < N && kb + tx < K)
            out[(size_t)n * K + kb + tx] = f2bf16u(tile[tx][ty + j * 8]);
    }
}

// ---------------- adaLN: mod = silu(c) @ adaln_w + adaln_b ----------------
__global__ __launch_bounds__(256) void k_mod(const float* __restrict__ cvec,
                                             const float* __restrict__ w,
                                             const float* __restrict__ bias,
                                             float* __restrict__ mod) {
    const int col = blockIdx.x * 256 + threadIdx.x;
    const int bg = blockIdx.y * 8;
    __shared__ float sc[8][HID];
    for (int t = threadIdx.x; t < 8 * HID; t += 256) {
        int bb = t / HID, k = t % HID;
        float v = cvec[(bg + bb) * HID + k];
        sc[bb][k] = v / (1.f + __expf(-v));
    }
    __syncthreads();
    float acc[8];
    const float bv = bias[col];
    #pragma unroll
    for (int b = 0; b < 8; b++) acc[b] = bv;
    for (int k = 0; k < HID; k++) {
        float wv = w[(size_t)k * MODW + col];
        #pragma unroll
        for (int b = 0; b < 8; b++) acc[b] += sc[b][k] * wv;
    }
    #pragma unroll
    for (int b = 0; b < 8; b++) mod[(size_t)(bg + b) * MODW + col] = acc[b];
}

// ---------------- layernorm + modulate -> bf16 ----------------
__global__ __launch_bounds__(256) void k_ln_mod(const float* __restrict__ x,
                                                const float* __restrict__ mod,
                                                int shift_chunk, int scale_chunk,
                                                unsigned short* __restrict__ out,
                                                int r0) {
    const size_t row = blockIdx.x;
    const int b = (int)((r0 + row) >> 10);
    const float4* xr = (const float4*)(x + row * HID);
    const int t = threadIdx.x;
    float4 v0 = xr[t];
    float4 v1 = make_float4(0.f, 0.f, 0.f, 0.f);
    if (t < 32) v1 = xr[256 + t];
    float s  = v0.x + v0.y + v0.z + v0.w + v1.x + v1.y + v1.z + v1.w;
    float s2 = v0.x*v0.x + v0.y*v0.y + v0.z*v0.z + v0.w*v0.w
             + v1.x*v1.x + v1.y*v1.y + v1.z*v1.z + v1.w*v1.w;
    block_reduce2(s, s2);
    const float mean = s * (1.f / HID);
    float var = s2 * (1.f / HID) - mean * mean;
    const float rstd = rsqrtf(fmaxf(var, 0.f) + 1e-6f);
    const float* shiftp = mod + (size_t)b * MODW + shift_chunk * HID;
    const float* scalep = mod + (size_t)b * MODW + scale_chunk * HID;
    {
        float4 sc = *(const float4*)(scalep + 4 * t);
        float4 sh = *(const float4*)(shiftp + 4 * t);
        float y0 = ((v0.x - mean) * rstd) * (1.f + sc.x) + sh.x;
        float y1 = ((v0.y - mean) * rstd) * (1.f + sc.y) + sh.y;
        float y2 = ((v0.z - mean) * rstd) * (1.f + sc.z) + sh.z;
        float y3 = ((v0.w - mean) * rstd) * (1.f + sc.w) + sh.w;
        uint2 o; o.x = pack2(y0, y1); o.y = pack2(y2, y3);
        *(uint2*)(out + row * HID + 4 * t) = o;
    }
    if (t < 32) {
        int col = 1024 + 4 * t;
        float4 sc = *(const float4*)(scalep + col);
        float4 sh = *(const float4*)(shiftp + col);
        float y0 = ((v1.x - mean) * rstd) * (1.f + sc.x) + sh.x;
        float y1 = ((v1.y - mean) * rstd) * (1.f + sc.y) + sh.y;
        float y2 = ((v1.z - mean) * rstd) * (1.f + sc.z) + sh.z;
        float y3 = ((v1.w - mean) * rstd) * (1.f + sc.w) + sh.w;
        uint2 o; o.x = pack2(y0, y1); o.y = pack2(y2, y3);
        *(uint2*)(out + row * HID + col) = o;
    }
}

// ---------------- bf16 MFMA GEMM: C = A(M,K) * BT(N,K)^T + bias ----------------
// 128x128 tile, BK=64, global_load_lds staging, source-swizzled LDS (0 bank conflicts),
// 2D supertile (GM x GN) + m204 bijective XCD chunk swizzle for L2/L3 locality.
// EPI 0: out fp32 = acc + bias
// EPI 1: out bf16 = gelu(acc + bias)
// EPI 2: out fp32 = resid + gate[b,col]*(acc + bias)   (b from global row r0+row)
// EPI 3: split: fcol<HID -> outp(fp32, stride HID, bias) else out2(fp32, stride 768, bias2)
template <int EPI>
__global__ __launch_bounds__(256, 5) void k_gemm_bt(
        const unsigned short* __restrict__ A, const unsigned short* __restrict__ BT,
        const float* __restrict__ bias, const float* __restrict__ bias2,
        void* __restrict__ outp, float* __restrict__ out2,
        const float* __restrict__ resid, const float* __restrict__ gate,
        int Np, int K, int r0, int MBk, int GM, int GN) {
    __shared__ __align__(16) char As[16384];
    __shared__ __align__(16) char Bs[16384];
    const int tid  = threadIdx.x;
    const int lane = tid & 63;
    const int wave = tid >> 6;
    const int wr = wave >> 1, wc = wave & 1;

    // ---- supertile + XCD-chunk block swizzle (bijective) ----
    const int P  = GM * GN;               // blocks per supertile
    const int s  = blockIdx.x / P;
    const int rr = blockIdx.x % P;
    const int q8 = P >> 3, r8 = P & 7;
    const int xcd = rr & 7, off8 = rr >> 3;
    const int rw  = (xcd < r8 ? xcd * (q8 + 1) : r8 * (q8 + 1) + (xcd - r8) * q8) + off8;
    const int mloc = rw / GN, nloc = rw % GN;
    const int smCount = MBk / GM;
    const int sm = s % smCount, sn = s / smCount;
    const int m0 = (sm * GM + mloc) << 7;
    const int n0 = (sn * GN + nloc) << 7;

    // staging: wave w covers rows 32w..32w+31 (4 chunks of 8 rows = 1KB each).
    const int srow = lane >> 3;                 // 0..7
    const int kgrp = (lane & 7) ^ srow;         // swizzled k-group for this lane
    const unsigned short* aS = A  + (size_t)(m0 + 32 * wave + srow) * K + kgrp * 8;
    const unsigned short* bS = BT + (size_t)(n0 + 32 * wave + srow) * K + kgrp * 8;
    const size_t chunkK = (size_t)8 * K;        // 8 rows per chunk
    char* aD = As + wave * 4096;
    char* bD = Bs + wave * 4096;

    // fragment read offsets: byte = r*128 + ((kg ^ (r&7))<<4); kk=1 -> ^64
    const int hi = lane >> 4;
    const int lo = lane & 15;
    const int swz = ((hi ^ (lo & 7)) << 4);
    int aoff[4], boff[4];
    #pragma unroll
    for (int i = 0; i < 4; i++) {
        aoff[i] = (wr * 64 + i * 16 + lo) * 128 + swz;
        boff[i] = (wc * 64 + i * 16 + lo) * 128 + swz;
    }

    f32x4 acc[4][4];
    #pragma unroll
    for (int i = 0; i < 4; i++)
        #pragma unroll
        for (int j = 0; j < 4; j++)
            acc[i][j] = (f32x4){0.f, 0.f, 0.f, 0.f};

    const int nk = K >> 6;
    for (int kt = 0; kt < nk; ++kt) {
        __syncthreads();
        #pragma unroll
        for (int j = 0; j < 4; j++) {
            gload16(aS + j * chunkK, aD + j * 1024);
            gload16(bS + j * chunkK, bD + j * 1024);
        }
        aS += 64; bS += 64;
        __syncthreads();
        #pragma unroll
        for (int kk = 0; kk < 2; kk++) {
            const int kx = kk << 6;
            short8 bfr[4];
            #pragma unroll
            for (int j = 0; j < 4; j++)
                bfr[j] = *(const short8*)(Bs + (boff[j] ^ kx));
            #pragma unroll
            for (int i = 0; i < 4; i++) {
                short8 af = *(const short8*)(As + (aoff[i] ^ kx));
                #pragma unroll
                for (int j = 0; j < 4; j++)
                    acc[i][j] = __builtin_amdgcn_mfma_f32_16x16x32_bf16(af, bfr[j], acc[i][j], 0, 0, 0);
            }
        }
    }

    // epilogue. C/D layout: col = lane&15, row = 4*(lane>>4)+reg
    const int c_l = lane & 15;
    const int r_l = (lane >> 4) << 2;
    #pragma unroll
    for (int j = 0; j < 4; j++) {
        const int fcol = n0 + wc * 64 + j * 16 + c_l;
        float bv;
        if constexpr (EPI == 3) bv = (fcol < HID) ? bias[fcol] : bias2[fcol - HID];
        else                    bv = bias[fcol];
        #pragma unroll
        for (int i = 0; i < 4; i++) {
            const int frow = m0 + wr * 64 + i * 16 + r_l;
            #pragma unroll
            for (int r = 0; r < 4; r++) {
                float v = acc[i][j][r] + bv;
                if constexpr (EPI == 0) {
                    ((float*)outp)[(size_t)(frow + r) * Np + fcol] = v;
                } else if constexpr (EPI == 1) {
                    ((unsigned short*)outp)[(size_t)(frow + r) * Np + fcol] = f2bf16u(gelu_tanh(v));
                } else if constexpr (EPI == 2) {
                    const size_t off = (size_t)(frow + r) * Np + fcol;
                    const int bb = (r0 + frow + r) >> 10;
                    ((float*)outp)[off] = resid[off] + gate[(size_t)bb * MODW + fcol] * v;
                } else {
                    if (fcol < HID) ((float*)outp)[(size_t)(frow + r) * HID + fcol] = v;
                    else            out2[(size_t)(frow + r) * (2 * KVC) + (fcol - HID)] = v;
                }
            }
        }
    }
}

// ---------------- focused() norm scales for q (12 heads) and k (4 heads) ----------------
__global__ __launch_bounds__(256) void k_fnorms(const float* __restrict__ ql,
                                                const float* __restrict__ kvl,
                                                float* __restrict__ qscale,
                                                float* __restrict__ kscale,
                                                int b0) {
    const int b = blockIdx.x >> 4, hh = blockIdx.x & 15;
    const float* base;
    int stride;
    if (hh < HEADS) { base = ql  + (size_t)b * SEQ * HID + hh * HD;           stride = HID; }
    else            { base = kvl + (size_t)b * SEQ * (2*KVC) + (hh-HEADS)*HD; stride = 2*KVC; }
    float s2 = 0.f, s6 = 0.f;
    for (int i = threadIdx.x; i < SEQ * (HD / 4); i += 256) {
        int n = i / 24, dq = i % 24;
        float4 v = *(const float4*)(base + (size_t)n * stride + dq * 4);
        float a;
        a = fmaxf(v.x, 0.f); { float a2 = a*a; s2 += a2; s6 += a2*a2*a2; }
        a = fmaxf(v.y, 0.f); { float a2 = a*a; s2 += a2; s6 += a2*a2*a2; }
        a = fmaxf(v.z, 0.f); { float a2 = a*a; s2 += a2; s6 += a2*a2*a2; }
        a = fmaxf(v.w, 0.f); { float a2 = a*a; s2 += a2; s6 += a2*a2*a2; }
    }
    block_reduce2(s2, s6);
    if (threadIdx.x == 0) {
        float an  = sqrtf(s2);
        float apn = (s6 == 0.f) ? 1e-12f : sqrtf(s6);
        float sc = an / apn;
        if (hh < HEADS) qscale[(b0 + b) * HEADS + hh] = sc;
        else            kscale[(b0 + b) * KVH + (hh - HEADS)] = sc;
    }
}

// ---------------- depthwise 3x3 conv: 4 channels/thread, float4 loads ----------------
__global__ __launch_bounds__(256) void k_dwconv(const float* __restrict__ kvl,
                                                const float* __restrict__ w,
                                                const float* __restrict__ bias,
                                                unsigned short* __restrict__ vd) {
    const int idx = blockIdx.x * 256 + threadIdx.x;   // < CROWS*96
    const int c4 = idx % 96;
    const int bn = idx / 96;
    const int n = bn & 1023;
    const int b = bn >> 10;
    const int y = n >> 5, xx = n & 31;
    float4 acc = *(const float4*)(bias + c4 * 4);
    #pragma unroll
    for (int dy = -1; dy <= 1; dy++) {
        const int yy = y + dy;
        if ((unsigned)yy > 31u) continue;
        #pragma unroll
        for (int dx = -1; dx <= 1; dx++) {
            const int xc = xx + dx;
            if ((unsigned)xc > 31u) continue;
            float4 v = *(const float4*)(kvl + ((size_t)b * SEQ + yy * 32 + xc) * (2*KVC) + KVC + c4 * 4);
            const int t = (dy + 1) * 3 + (dx + 1);
            acc.x += w[(c4 * 4 + 0) * 9 + t] * v.x;
            acc.y += w[(c4 * 4 + 1) * 9 + t] * v.y;
            acc.z += w[(c4 * 4 + 2) * 9 + t] * v.z;
            acc.w += w[(c4 * 4 + 3) * 9 + t] * v.w;
        }
    }
    uint2 o; o.x = pack2(acc.x, acc.y); o.y = pack2(acc.z, acc.w);
    *(uint2*)(vd + (size_t)idx * 4) = o;
}

// ---------------- kvmat = focused(k)^T @ v  (per local b, kv-head: 96x96) ----------------
__global__ __launch_bounds__(256) void k_kvmat(const float* __restrict__ kvl,
                                               const float* __restrict__ kscale,
                                               float* __restrict__ kvmat,
                                               int b0) {
    const int b = blockIdx.x >> 2, h = blockIdx.x & 3;
    const float sc = kscale[(b0 + b) * KVH + h];
    __shared__ float Ks[16][96], Vs[16][96];
    float acc[6][6];
    #pragma unroll
    for (int i = 0; i < 6; i++)
        #pragma unroll
        for (int j = 0; j < 6; j++) acc[i][j] = 0.f;
    const int ti = threadIdx.x >> 4, tj = threadIdx.x & 15;
    const float* kbase = kvl + (size_t)b * SEQ * (2*KVC) + h * HD;
    const float* vbase = kbase + KVC;
    for (int n0 = 0; n0 < SEQ; n0 += 16) {
        __syncthreads();
        for (int i = threadIdx.x; i < 16 * 96; i += 256) {
            int nn = i / 96, d = i % 96;
            float kv_ = kbase[(size_t)(n0 + nn) * (2*KVC) + d];
            float r = fmaxf(kv_, 0.f);
            Ks[nn][d] = sc * r * r * r;
            Vs[nn][d] = vbase[(size_t)(n0 + nn) * (2*KVC) + d];
        }
        __syncthreads();
        for (int nn = 0; nn < 16; nn++) {
            float av[6], bv[6];
            #pragma unroll
            for (int i = 0; i < 6; i++) av[i] = Ks[nn][ti * 6 + i];
            #pragma unroll
            for (int j = 0; j < 6; j++) bv[j] = Vs[nn][tj * 6 + j];
            #pragma unroll
            for (int i = 0; i < 6; i++)
                #pragma unroll
                for (int j = 0; j < 6; j++) acc[i][j] += av[i] * bv[j];
        }
    }
    float* out = kvmat + (size_t)(b * KVH + h) * 96 * 96;
    #pragma unroll
    for (int i = 0; i < 6; i++)
        #pragma unroll
        for (int j = 0; j < 6; j++)
            out[(size_t)(ti * 6 + i) * 96 + tj * 6 + j] = acc[i][j];
}

// ---------------- o = focused(q) @ kvmat[h%4] + vd[h%4], out bf16 chunk-local ----------------
__global__ __launch_bounds__(256) void k_ogemm(const float* __restrict__ ql,
                                               const float* __restrict__ qscale,
                                               const float* __restrict__ kvmat,
                                               const unsigned short* __restrict__ vd,
                                               unsigned short* __restrict__ obuf,
                                               int b0) {
    const int rc = blockIdx.x;   // 0..7 row chunks of 128
    const int h  = blockIdx.y;   // 0..11
    const int b  = blockIdx.z;   // local batch
    const int kvh = h & 3;
    __shared__ float Ms[96][96];
    for (int i = threadIdx.x; i < 96 * 96; i += 256)
        Ms[i / 96][i % 96] = kvmat[(size_t)(b * KVH + kvh) * 9216 + i];
    const float qs = qscale[(b0 + b) * HEADS + h];
    __syncthreads();
    const int rowg = threadIdx.x >> 3;  // 0..31 (x4 rows)
    const int colg = threadIdx.x & 7;   // 0..7  (x12 cols)
    const int n_base = rc * 128 + rowg * 4;
    const float* qb = ql + ((size_t)(b * SEQ + n_base)) * HID + h * HD;
    float acc[4][12];
    #pragma unroll
    for (int r = 0; r < 4; r++)
        #pragma unroll
        for (int j = 0; j < 12; j++) acc[r][j] = 0.f;
    for (int k0 = 0; k0 < 96; k0 += 4) {
        float q_[4][4];
        #pragma unroll
        for (int r = 0; r < 4; r++) {
            float4 t = *(const float4*)(qb + (size_t)r * HID + k0);
            float a;
            a = fmaxf(t.x, 0.f); q_[r][0] = qs * a * a * a;
            a = fmaxf(t.y, 0.f); q_[r][1] = qs * a * a * a;
            a = fmaxf(t.z, 0.f); q_[r][2] = qs * a * a * a;
            a = fmaxf(t.w, 0.f); q_[r][3] = qs * a * a * a;
        }
        #pragma unroll
        for (int kk = 0; kk < 4; kk++) {
            float bv[12];
            #pragma unroll
            for (int j = 0; j < 12; j += 4) {
                float4 t = *(const float4*)&Ms[k0 + kk][colg * 12 + j];
                bv[j] = t.x; bv[j+1] = t.y; bv[j+2] = t.z; bv[j+3] = t.w;
            }
            #pragma unroll
            for (int r = 0; r < 4; r++)
                #pragma unroll
                for (int j = 0; j < 12; j++) acc[r][j] += q_[r][kk] * bv[j];
        }
    }
    const unsigned short* vdb = vd + ((size_t)(b * SEQ + n_base)) * KVC + kvh * HD + colg * 12;
    unsigned short* ob = obuf + ((size_t)(b * SEQ + n_base)) * HID + h * HD + colg * 12;
    for (int r = 0; r < 4; r++)
        for (int j = 0; j < 12; j++) {
            float v = acc[r][j] + bfu2f(vdb[(size_t)r * KVC + j]);
            ob[(size_t)r * HID + j] = f2bf16u(v);
        }
}

// ---------------- fixed workspace layout ----------------
constexpr size_t WQT_OFF  = 0;                                    // 1152*1152 bf16
constexpr size_t WKVT_OFF = WQT_OFF  + (size_t)1152*1152*2;       // 768*1152 bf16 (adjacent: [1920][1152])
constexpr size_t WPT_OFF  = WKVT_OFF + (size_t)768*1152*2;        // 1152*1152 bf16
constexpr size_t W1T_OFF  = WPT_OFF  + (size_t)1152*1152*2;       // 4608*1152 bf16
constexpr size_t W2T_OFF  = W1T_OFF  + (size_t)4608*1152*2;       // 1152*4608 bf16
constexpr size_t MOD_OFF  = W2T_OFF  + (size_t)1152*4608*2;       // 32*6912 f32
constexpr size_t QSC_OFF  = MOD_OFF  + (size_t)BB*MODW*4;         // 32*12 f32
constexpr size_t KSC_OFF  = QSC_OFF  + 1536;                      // 32*4 f32
constexpr size_t DYN_OFF  = KSC_OFF  + 512;                       // chunked scratch

static int pick_gn(int nb) {
    for (int g = 12; g >= 2; --g) if (nb % g == 0) return g;
    return 1;
}

extern "C" void kernel_launch(void* const* d_in, const int* in_sizes, int n_in,
                              void* d_out, int out_size, void* d_ws, size_t ws_size,
                              hipStream_t stream) {
    (void)in_sizes; (void)n_in; (void)out_size;

    const float* x       = (const float*)d_in[0];
    const float* cvec    = (const float*)d_in[1];
    const float* wq_w    = (const float*)d_in[2];
    const float* wq_b    = (const float*)d_in[3];
    const float* wkv_w   = (const float*)d_in[4];
    const float* wkv_b   = (const float*)d_in[5];
    const float* dwc_w   = (const float*)d_in[6];
    const float* dwc_b   = (const float*)d_in[7];
    const float* proj_w  = (const float*)d_in[8];
    const float* proj_b  = (const float*)d_in[9];
    const float* adaln_w = (const float*)d_in[10];
    const float* adaln_b = (const float*)d_in[11];
    const float* mlp_w1  = (const float*)d_in[12];
    const float* mlp_b1  = (const float*)d_in[13];
    const float* mlp_w2  = (const float*)d_in[14];
    const float* mlp_b2  = (const float*)d_in[15];

    // ---- adaptive chunk size: largest CB batches whose scratch fits ws_size ----
    int CB = 0;
    for (int cb = 32; cb >= 1; cb >>= 1) {
        size_t rows = (size_t)cb * 1024;
        size_t attn = rows * (1152*2 + 1152*4 + 768*4 + 384*2 + 1152*2)
                    + (size_t)cb * 4 * 9216 * 4;
        size_t mlp  = rows * (1152*2 + 4608*2);
        size_t need = DYN_OFF + (attn > mlp ? attn : mlp);
        if (need <= ws_size) { CB = cb; break; }
    }
    if (CB == 0) return;
    const size_t CROWS = (size_t)CB * 1024;

    char* ws = (char*)d_ws;
    unsigned short* WQT  = (unsigned short*)(ws + WQT_OFF);   // rows 0..1151 of merged [1920][1152]
    unsigned short* WKVT = (unsigned short*)(ws + WKVT_OFF);  // rows 1152..1919
    unsigned short* WPT  = (unsigned short*)(ws + WPT_OFF);
    unsigned short* W1T  = (unsigned short*)(ws + W1T_OFF);
    unsigned short* W2T  = (unsigned short*)(ws + W2T_OFF);
    float*          MODp = (float*)(ws + MOD_OFF);
    float*          QSC  = (float*)(ws + QSC_OFF);
    float*          KSC  = (float*)(ws + KSC_OFF);
    char* dyn = ws + DYN_OFF;
    unsigned short* XMc  = (unsigned short*)dyn;
    float*          QLc  = (float*)(dyn + CROWS * 1152 * 2);
    float*          KVLc = (float*)((char*)QLc + CROWS * 1152 * 4);
    float*          KVMc = (float*)((char*)KVLc + CROWS * 768 * 4);
    unsigned short* VDc  = (unsigned short*)((char*)KVMc + (size_t)CB * 4 * 9216 * 4);
    unsigned short* OBc  = (unsigned short*)((char*)VDc + CROWS * 384 * 2);
    unsigned short* XM2  = (unsigned short*)dyn;
    unsigned short* Hc   = (unsigned short*)(dyn + CROWS * 1152 * 2);
    float*          OUT  = (float*)d_out;

    dim3 tb(32, 8);
    k_transpose_bf16<<<dim3(36, 36),  tb, 0, stream>>>(wq_w,   WQT,  1152, 1152);
    k_transpose_bf16<<<dim3(36, 24),  tb, 0, stream>>>(wkv_w,  WKVT, 1152, 768);
    k_transpose_bf16<<<dim3(36, 36),  tb, 0, stream>>>(proj_w, WPT,  1152, 1152);
    k_transpose_bf16<<<dim3(36, 144), tb, 0, stream>>>(mlp_w1, W1T,  1152, 4608);
    k_transpose_bf16<<<dim3(144, 36), tb, 0, stream>>>(mlp_w2, W2T,  4608, 1152);

    k_mod<<<dim3(27, 4), 256, 0, stream>>>(cvec, adaln_w, adaln_b, MODp);

    const int MB = (int)(CROWS >> 7);      // 128-row M blocks per chunk
    const int GM = MB < 16 ? MB : 16;
    const int GN_QKV  = pick_gn(15);       // 5
    const int GN_PROJ = pick_gn(9);        // 9
    const int GN_MLP1 = pick_gn(36);       // 12
    const int GN_MLP2 = pick_gn(9);        // 9

    // --- attention branch, chunked over batches ---
    for (int b0 = 0; b0 < BB; b0 += CB) {
        const int r0 = b0 << 10;
        const float* xch = x + (size_t)r0 * HID;
        k_ln_mod<<<(int)CROWS, 256, 0, stream>>>(xch, MODp, 0, 1, XMc, r0);
        k_gemm_bt<3><<<15 * MB, 256, 0, stream>>>(XMc, WQT, wq_b, wkv_b, QLc, KVLc,
                                                  nullptr, nullptr, 1152, 1152, 0, MB, GM, GN_QKV);
        k_fnorms<<<CB * 16, 256, 0, stream>>>(QLc, KVLc, QSC, KSC, b0);
        k_dwconv<<<(int)(CROWS * 96 / 256), 256, 0, stream>>>(KVLc, dwc_w, dwc_b, VDc);
        k_kvmat<<<CB * 4, 256, 0, stream>>>(KVLc, KSC, KVMc, b0);
        k_ogemm<<<dim3(8, HEADS, CB), 256, 0, stream>>>(QLc, QSC, KVMc, VDc, OBc, b0);
        k_gemm_bt<2><<<9 * MB, 256, 0, stream>>>(OBc, WPT, proj_b, nullptr, OUT + (size_t)r0 * HID, nullptr,
                                                 xch, MODp + 2 * HID, 1152, 1152, r0, MB, GM, GN_PROJ);
    }

    // --- MLP branch, chunked over rows (d_out now holds x1 = x + gate*attn) ---
    for (int r0 = 0; r0 < ROWS; r0 += (int)CROWS) {
        float* x1ch = OUT + (size_t)r0 * HID;
        k_ln_mod<<<(int)CROWS, 256, 0, stream>>>(x1ch, MODp, 3, 4, XM2, r0);
        k_gemm_bt<1><<<36 * MB, 256, 0, stream>>>(XM2, W1T, mlp_b1, nullptr, Hc, nullptr,
                                                  nullptr, nullptr, 4608, 1152, 0, MB, GM, GN_MLP1);
        k_gemm_bt<2><<<9 * MB, 256, 0, stream>>>(Hc, W2T, mlp_b2, nullptr, x1ch, nullptr,
                                                 x1ch, MODp + 5 * HID, 1152, 4608, r0, MB, GM, GN_MLP2);
    }
}

// Round 5
// 2210.617 us; speedup vs baseline: 1.6851x; 1.6851x over previous
//
#include <hip/hip_runtime.h>
#include <hip/hip_bf16.h>
#include <cstdint>
#include <cstddef>

#define DEV __device__ __forceinline__

// ---------------- problem constants ----------------
constexpr int BB    = 32;
constexpr int SEQ   = 1024;
constexpr int HID   = 1152;
constexpr int HEADS = 12;
constexpr int KVH   = 4;
constexpr int HD    = 96;
constexpr int KVC   = 384;   // KVH*HD
constexpr int MLPD  = 4608;
constexpr int ROWS  = BB * SEQ;          // 32768
constexpr int MODW  = 6 * HID;           // 6912

typedef __attribute__((ext_vector_type(8))) short short8;
typedef __attribute__((ext_vector_type(4))) float f32x4;

// ---------------- helpers ----------------
DEV float bfu2f(unsigned short u) {
    unsigned v = ((unsigned)u) << 16;
    return __builtin_bit_cast(float, v);
}
DEV unsigned short f2bf16u(float f) {
    unsigned u = __builtin_bit_cast(unsigned, f);
    u += 0x7FFFu + ((u >> 16) & 1u);   // RNE
    return (unsigned short)(u >> 16);
}
DEV unsigned pack2(float a, float b) {
    return (unsigned)f2bf16u(a) | ((unsigned)f2bf16u(b) << 16);
}
DEV float gelu_tanh(float x) {
    float x3 = x * x * x;
    float t = tanhf(0.7978845608028654f * (x + 0.044715f * x3));
    return 0.5f * x * (1.f + t);
}

// async global->LDS, 16B per lane. LDS dest must be wave-uniform base (+lane*16).
DEV void gload16(const void* g, void* l) {
    __builtin_amdgcn_global_load_lds(
        (const __attribute__((address_space(1))) unsigned int*)g,
        (__attribute__((address_space(3))) unsigned int*)l,
        16, 0, 0);
}

// block reduce of two floats, blockDim.x == 256
DEV void block_reduce2(float& a, float& b) {
    #pragma unroll
    for (int off = 32; off > 0; off >>= 1) {
        a += __shfl_down(a, off, 64);
        b += __shfl_down(b, off, 64);
    }
    __shared__ float sa[4], sb[4];
    int w = threadIdx.x >> 6;
    if ((threadIdx.x & 63) == 0) { sa[w] = a; sb[w] = b; }
    __syncthreads();
    a = sa[0] + sa[1] + sa[2] + sa[3];
    b = sb[0] + sb[1] + sb[2] + sb[3];
    __syncthreads();
}

// ---------------- weight transpose + bf16 convert ----------------
__global__ void k_transpose_bf16(const float* __restrict__ in,
                                 unsigned short* __restrict__ out, int K, int N) {
    __shared__ float tile[32][33];
    int kb = blockIdx.x * 32;
    int nb = blockIdx.y * 32;
    int tx = threadIdx.x, ty = threadIdx.y;   // (32, 8)
    #pragma unroll
    for (int j = 0; j < 4; j++) {
        int k = kb + ty + j * 8;
        tile[ty + j * 8][tx] = (k < K && nb + tx < N) ? in[(size_t)k * N + nb + tx] : 0.f;
    }
    __syncthreads();
    #pragma unroll
    for (int j = 0; j < 4; j++) {
        int n = nb + ty + j * 8;
        if (n < N && kb + tx < K)
            out[(size_t)n * K + kb + tx] = f2bf16u(tile[tx][ty + j * 8]);
    }
}

// ---------------- adaLN: mod = silu(c) @ adaln_w + adaln_b ----------------
__global__ __launch_bounds__(256) void k_mod(const float* __restrict__ cvec,
                                             const float* __restrict__ w,
                                             const float* __restrict__ bias,
                                             float* __restrict__ mod) {
    const int col = blockIdx.x * 256 + threadIdx.x;
    const int bg = blockIdx.y * 8;
    __shared__ float sc[8][HID];
    for (int t = threadIdx.x; t < 8 * HID; t += 256) {
        int bb = t / HID, k = t % HID;
        float v = cvec[(bg + bb) * HID + k];
        sc[bb][k] = v / (1.f + __expf(-v));
    }
    __syncthreads();
    float acc[8];
    const float bv = bias[col];
    #pragma unroll
    for (int b = 0; b < 8; b++) acc[b] = bv;
    for (int k = 0; k < HID; k++) {
        float wv = w[(size_t)k * MODW + col];
        #pragma unroll
        for (int b = 0; b < 8; b++) acc[b] += sc[b][k] * wv;
    }
    #pragma unroll
    for (int b = 0; b < 8; b++) mod[(size_t)(bg + b) * MODW + col] = acc[b];
}

// ---------------- layernorm + modulate -> bf16 ----------------
__global__ __launch_bounds__(256) void k_ln_mod(const float* __restrict__ x,
                                                const float* __restrict__ mod,
                                                int shift_chunk, int scale_chunk,
                                                unsigned short* __restrict__ out,
                                                int r0) {
    const size_t row = blockIdx.x;
    const int b = (int)((r0 + row) >> 10);
    const float4* xr = (const float4*)(x + row * HID);
    const int t = threadIdx.x;
    float4 v0 = xr[t];
    float4 v1 = make_float4(0.f, 0.f, 0.f, 0.f);
    if (t < 32) v1 = xr[256 + t];
    float s  = v0.x + v0.y + v0.z + v0.w + v1.x + v1.y + v1.z + v1.w;
    float s2 = v0.x*v0.x + v0.y*v0.y + v0.z*v0.z + v0.w*v0.w
             + v1.x*v1.x + v1.y*v1.y + v1.z*v1.z + v1.w*v1.w;
    block_reduce2(s, s2);
    const float mean = s * (1.f / HID);
    float var = s2 * (1.f / HID) - mean * mean;
    const float rstd = rsqrtf(fmaxf(var, 0.f) + 1e-6f);
    const float* shiftp = mod + (size_t)b * MODW + shift_chunk * HID;
    const float* scalep = mod + (size_t)b * MODW + scale_chunk * HID;
    {
        float4 sc = *(const float4*)(scalep + 4 * t);
        float4 sh = *(const float4*)(shiftp + 4 * t);
        float y0 = ((v0.x - mean) * rstd) * (1.f + sc.x) + sh.x;
        float y1 = ((v0.y - mean) * rstd) * (1.f + sc.y) + sh.y;
        float y2 = ((v0.z - mean) * rstd) * (1.f + sc.z) + sh.z;
        float y3 = ((v0.w - mean) * rstd) * (1.f + sc.w) + sh.w;
        uint2 o; o.x = pack2(y0, y1); o.y = pack2(y2, y3);
        *(uint2*)(out + row * HID + 4 * t) = o;
    }
    if (t < 32) {
        int col = 1024 + 4 * t;
        float4 sc = *(const float4*)(scalep + col);
        float4 sh = *(const float4*)(shiftp + col);
        float y0 = ((v1.x - mean) * rstd) * (1.f + sc.x) + sh.x;
        float y1 = ((v1.y - mean) * rstd) * (1.f + sc.y) + sh.y;
        float y2 = ((v1.z - mean) * rstd) * (1.f + sc.z) + sh.z;
        float y3 = ((v1.w - mean) * rstd) * (1.f + sc.w) + sh.w;
        uint2 o; o.x = pack2(y0, y1); o.y = pack2(y2, y3);
        *(uint2*)(out + row * HID + col) = o;
    }
}

// ---------------- bf16 MFMA GEMM: C = A(M,K) * BT(N,K)^T + bias ----------------
// 128x128 tile, BK=64, global_load_lds staging, source-swizzled LDS (0 bank conflicts),
// 2D supertile (GM x GN) + m204 bijective XCD chunk swizzle for L2/L3 locality.
// __launch_bounds__(256,4): 64 VGPR + 64 AGPR = 128/wave exactly; (256,5) SPILLS the
// accumulator to scratch (round-4 regression: WRITE_SIZE 0.27->2.13 GB). Do not raise.
// EPI 0: out fp32 = acc + bias
// EPI 1: out bf16 = gelu(acc + bias)
// EPI 2: out fp32 = resid + gate[b,col]*(acc + bias)   (b from global row r0+row)
// EPI 3: split: fcol<HID -> outp(fp32, stride HID, bias) else out2(fp32, stride 768, bias2)
template <int EPI>
__global__ __launch_bounds__(256, 4) void k_gemm_bt(
        const unsigned short* __restrict__ A, const unsigned short* __restrict__ BT,
        const float* __restrict__ bias, const float* __restrict__ bias2,
        void* __restrict__ outp, float* __restrict__ out2,
        const float* __restrict__ resid, const float* __restrict__ gate,
        int Np, int K, int r0, int MBk, int GM, int GN) {
    __shared__ __align__(16) char As[16384];
    __shared__ __align__(16) char Bs[16384];
    const int tid  = threadIdx.x;
    const int lane = tid & 63;
    const int wave = tid >> 6;
    const int wr = wave >> 1, wc = wave & 1;

    // ---- supertile + XCD-chunk block swizzle (bijective) ----
    const int P  = GM * GN;               // blocks per supertile
    const int s  = blockIdx.x / P;
    const int rr = blockIdx.x % P;
    const int q8 = P >> 3, r8 = P & 7;
    const int xcd = rr & 7, off8 = rr >> 3;
    const int rw  = (xcd < r8 ? xcd * (q8 + 1) : r8 * (q8 + 1) + (xcd - r8) * q8) + off8;
    const int mloc = rw / GN, nloc = rw % GN;
    const int smCount = MBk / GM;
    const int sm = s % smCount, sn = s / smCount;
    const int m0 = (sm * GM + mloc) << 7;
    const int n0 = (sn * GN + nloc) << 7;

    // staging: wave w covers rows 32w..32w+31 (4 chunks of 8 rows = 1KB each).
    const int srow = lane >> 3;                 // 0..7
    const int kgrp = (lane & 7) ^ srow;         // swizzled k-group for this lane
    const unsigned short* aS = A  + (size_t)(m0 + 32 * wave + srow) * K + kgrp * 8;
    const unsigned short* bS = BT + (size_t)(n0 + 32 * wave + srow) * K + kgrp * 8;
    const size_t chunkK = (size_t)8 * K;        // 8 rows per chunk
    char* aD = As + wave * 4096;
    char* bD = Bs + wave * 4096;

    // fragment read offsets: byte = r*128 + ((kg ^ (r&7))<<4); kk=1 -> ^64
    const int hi = lane >> 4;
    const int lo = lane & 15;
    const int swz = ((hi ^ (lo & 7)) << 4);
    int aoff[4], boff[4];
    #pragma unroll
    for (int i = 0; i < 4; i++) {
        aoff[i] = (wr * 64 + i * 16 + lo) * 128 + swz;
        boff[i] = (wc * 64 + i * 16 + lo) * 128 + swz;
    }

    f32x4 acc[4][4];
    #pragma unroll
    for (int i = 0; i < 4; i++)
        #pragma unroll
        for (int j = 0; j < 4; j++)
            acc[i][j] = (f32x4){0.f, 0.f, 0.f, 0.f};

    const int nk = K >> 6;
    for (int kt = 0; kt < nk; ++kt) {
        __syncthreads();
        #pragma unroll
        for (int j = 0; j < 4; j++) {
            gload16(aS + j * chunkK, aD + j * 1024);
            gload16(bS + j * chunkK, bD + j * 1024);
        }
        aS += 64; bS += 64;
        __syncthreads();
        #pragma unroll
        for (int kk = 0; kk < 2; kk++) {
            const int kx = kk << 6;
            short8 bfr[4];
            #pragma unroll
            for (int j = 0; j < 4; j++)
                bfr[j] = *(const short8*)(Bs + (boff[j] ^ kx));
            #pragma unroll
            for (int i = 0; i < 4; i++) {
                short8 af = *(const short8*)(As + (aoff[i] ^ kx));
                #pragma unroll
                for (int j = 0; j < 4; j++)
                    acc[i][j] = __builtin_amdgcn_mfma_f32_16x16x32_bf16(af, bfr[j], acc[i][j], 0, 0, 0);
            }
        }
    }

    // epilogue. C/D layout: col = lane&15, row = 4*(lane>>4)+reg
    const int c_l = lane & 15;
    const int r_l = (lane >> 4) << 2;
    #pragma unroll
    for (int j = 0; j < 4; j++) {
        const int fcol = n0 + wc * 64 + j * 16 + c_l;
        float bv;
        if constexpr (EPI == 3) bv = (fcol < HID) ? bias[fcol] : bias2[fcol - HID];
        else                    bv = bias[fcol];
        #pragma unroll
        for (int i = 0; i < 4; i++) {
            const int frow = m0 + wr * 64 + i * 16 + r_l;
            #pragma unroll
            for (int r = 0; r < 4; r++) {
                float v = acc[i][j][r] + bv;
                if constexpr (EPI == 0) {
                    ((float*)outp)[(size_t)(frow + r) * Np + fcol] = v;
                } else if constexpr (EPI == 1) {
                    ((unsigned short*)outp)[(size_t)(frow + r) * Np + fcol] = f2bf16u(gelu_tanh(v));
                } else if constexpr (EPI == 2) {
                    const size_t off = (size_t)(frow + r) * Np + fcol;
                    const int bb = (r0 + frow + r) >> 10;
                    ((float*)outp)[off] = resid[off] + gate[(size_t)bb * MODW + fcol] * v;
                } else {
                    if (fcol < HID) ((float*)outp)[(size_t)(frow + r) * HID + fcol] = v;
                    else            out2[(size_t)(frow + r) * (2 * KVC) + (fcol - HID)] = v;
                }
            }
        }
    }
}

// ---------------- focused() norm scales for q (12 heads) and k (4 heads) ----------------
__global__ __launch_bounds__(256) void k_fnorms(const float* __restrict__ ql,
                                                const float* __restrict__ kvl,
                                                float* __restrict__ qscale,
                                                float* __restrict__ kscale,
                                                int b0) {
    const int b = blockIdx.x >> 4, hh = blockIdx.x & 15;
    const float* base;
    int stride;
    if (hh < HEADS) { base = ql  + (size_t)b * SEQ * HID + hh * HD;           stride = HID; }
    else            { base = kvl + (size_t)b * SEQ * (2*KVC) + (hh-HEADS)*HD; stride = 2*KVC; }
    float s2 = 0.f, s6 = 0.f;
    for (int i = threadIdx.x; i < SEQ * (HD / 4); i += 256) {
        int n = i / 24, dq = i % 24;
        float4 v = *(const float4*)(base + (size_t)n * stride + dq * 4);
        float a;
        a = fmaxf(v.x, 0.f); { float a2 = a*a; s2 += a2; s6 += a2*a2*a2; }
        a = fmaxf(v.y, 0.f); { float a2 = a*a; s2 += a2; s6 += a2*a2*a2; }
        a = fmaxf(v.z, 0.f); { float a2 = a*a; s2 += a2; s6 += a2*a2*a2; }
        a = fmaxf(v.w, 0.f); { float a2 = a*a; s2 += a2; s6 += a2*a2*a2; }
    }
    block_reduce2(s2, s6);
    if (threadIdx.x == 0) {
        float an  = sqrtf(s2);
        float apn = (s6 == 0.f) ? 1e-12f : sqrtf(s6);
        float sc = an / apn;
        if (hh < HEADS) qscale[(b0 + b) * HEADS + hh] = sc;
        else            kscale[(b0 + b) * KVH + (hh - HEADS)] = sc;
    }
}

// ---------------- depthwise 3x3 conv: 4 channels/thread, float4 loads ----------------
__global__ __launch_bounds__(256) void k_dwconv(const float* __restrict__ kvl,
                                                const float* __restrict__ w,
                                                const float* __restrict__ bias,
                                                unsigned short* __restrict__ vd) {
    const int idx = blockIdx.x * 256 + threadIdx.x;   // < CROWS*96
    const int c4 = idx % 96;
    const int bn = idx / 96;
    const int n = bn & 1023;
    const int b = bn >> 10;
    const int y = n >> 5, xx = n & 31;
    float4 acc = *(const float4*)(bias + c4 * 4);
    #pragma unroll
    for (int dy = -1; dy <= 1; dy++) {
        const int yy = y + dy;
        if ((unsigned)yy > 31u) continue;
        #pragma unroll
        for (int dx = -1; dx <= 1; dx++) {
            const int xc = xx + dx;
            if ((unsigned)xc > 31u) continue;
            float4 v = *(const float4*)(kvl + ((size_t)b * SEQ + yy * 32 + xc) * (2*KVC) + KVC + c4 * 4);
            const int t = (dy + 1) * 3 + (dx + 1);
            acc.x += w[(c4 * 4 + 0) * 9 + t] * v.x;
            acc.y += w[(c4 * 4 + 1) * 9 + t] * v.y;
            acc.z += w[(c4 * 4 + 2) * 9 + t] * v.z;
            acc.w += w[(c4 * 4 + 3) * 9 + t] * v.w;
        }
    }
    uint2 o; o.x = pack2(acc.x, acc.y); o.y = pack2(acc.z, acc.w);
    *(uint2*)(vd + (size_t)idx * 4) = o;
}

// ---------------- kvmat = focused(k)^T @ v  (per local b, kv-head: 96x96) ----------------
__global__ __launch_bounds__(256) void k_kvmat(const float* __restrict__ kvl,
                                               const float* __restrict__ kscale,
                                               float* __restrict__ kvmat,
                                               int b0) {
    const int b = blockIdx.x >> 2, h = blockIdx.x & 3;
    const float sc = kscale[(b0 + b) * KVH + h];
    __shared__ float Ks[16][96], Vs[16][96];
    float acc[6][6];
    #pragma unroll
    for (int i = 0; i < 6; i++)
        #pragma unroll
        for (int j = 0; j < 6; j++) acc[i][j] = 0.f;
    const int ti = threadIdx.x >> 4, tj = threadIdx.x & 15;
    const float* kbase = kvl + (size_t)b * SEQ * (2*KVC) + h * HD;
    const float* vbase = kbase + KVC;
    for (int n0 = 0; n0 < SEQ; n0 += 16) {
        __syncthreads();
        for (int i = threadIdx.x; i < 16 * 96; i += 256) {
            int nn = i / 96, d = i % 96;
            float kv_ = kbase[(size_t)(n0 + nn) * (2*KVC) + d];
            float r = fmaxf(kv_, 0.f);
            Ks[nn][d] = sc * r * r * r;
            Vs[nn][d] = vbase[(size_t)(n0 + nn) * (2*KVC) + d];
        }
        __syncthreads();
        for (int nn = 0; nn < 16; nn++) {
            float av[6], bv[6];
            #pragma unroll
            for (int i = 0; i < 6; i++) av[i] = Ks[nn][ti * 6 + i];
            #pragma unroll
            for (int j = 0; j < 6; j++) bv[j] = Vs[nn][tj * 6 + j];
            #pragma unroll
            for (int i = 0; i < 6; i++)
                #pragma unroll
                for (int j = 0; j < 6; j++) acc[i][j] += av[i] * bv[j];
        }
    }
    float* out = kvmat + (size_t)(b * KVH + h) * 96 * 96;
    #pragma unroll
    for (int i = 0; i < 6; i++)
        #pragma unroll
        for (int j = 0; j < 6; j++)
            out[(size_t)(ti * 6 + i) * 96 + tj * 6 + j] = acc[i][j];
}

// ---------------- o = focused(q) @ kvmat[h%4] + vd[h%4], out bf16 chunk-local ----------------
__global__ __launch_bounds__(256) void k_ogemm(const float* __restrict__ ql,
                                               const float* __restrict__ qscale,
                                               const float* __restrict__ kvmat,
                                               const unsigned short* __restrict__ vd,
                                               unsigned short* __restrict__ obuf,
                                               int b0) {
    const int rc = blockIdx.x;   // 0..7 row chunks of 128
    const int h  = blockIdx.y;   // 0..11
    const int b  = blockIdx.z;   // local batch
    const int kvh = h & 3;
    __shared__ float Ms[96][96];
    for (int i = threadIdx.x; i < 96 * 96; i += 256)
        Ms[i / 96][i % 96] = kvmat[(size_t)(b * KVH + kvh) * 9216 + i];
    const float qs = qscale[(b0 + b) * HEADS + h];
    __syncthreads();
    const int rowg = threadIdx.x >> 3;  // 0..31 (x4 rows)
    const int colg = threadIdx.x & 7;   // 0..7  (x12 cols)
    const int n_base = rc * 128 + rowg * 4;
    const float* qb = ql + ((size_t)(b * SEQ + n_base)) * HID + h * HD;
    float acc[4][12];
    #pragma unroll
    for (int r = 0; r < 4; r++)
        #pragma unroll
        for (int j = 0; j < 12; j++) acc[r][j] = 0.f;
    for (int k0 = 0; k0 < 96; k0 += 4) {
        float q_[4][4];
        #pragma unroll
        for (int r = 0; r < 4; r++) {
            float4 t = *(const float4*)(qb + (size_t)r * HID + k0);
            float a;
            a = fmaxf(t.x, 0.f); q_[r][0] = qs * a * a * a;
            a = fmaxf(t.y, 0.f); q_[r][1] = qs * a * a * a;
            a = fmaxf(t.z, 0.f); q_[r][2] = qs * a * a * a;
            a = fmaxf(t.w, 0.f); q_[r][3] = qs * a * a * a;
        }
        #pragma unroll
        for (int kk = 0; kk < 4; kk++) {
            float bv[12];
            #pragma unroll
            for (int j = 0; j < 12; j += 4) {
                float4 t = *(const float4*)&Ms[k0 + kk][colg * 12 + j];
                bv[j] = t.x; bv[j+1] = t.y; bv[j+2] = t.z; bv[j+3] = t.w;
            }
            #pragma unroll
            for (int r = 0; r < 4; r++)
                #pragma unroll
                for (int j = 0; j < 12; j++) acc[r][j] += q_[r][kk] * bv[j];
        }
    }
    const unsigned short* vdb = vd + ((size_t)(b * SEQ + n_base)) * KVC + kvh * HD + colg * 12;
    unsigned short* ob = obuf + ((size_t)(b * SEQ + n_base)) * HID + h * HD + colg * 12;
    for (int r = 0; r < 4; r++)
        for (int j = 0; j < 12; j++) {
            float v = acc[r][j] + bfu2f(vdb[(size_t)r * KVC + j]);
            ob[(size_t)r * HID + j] = f2bf16u(v);
        }
}

// ---------------- fixed workspace layout ----------------
constexpr size_t WQT_OFF  = 0;                                    // 1152*1152 bf16
constexpr size_t WKVT_OFF = WQT_OFF  + (size_t)1152*1152*2;       // 768*1152 bf16 (adjacent: [1920][1152])
constexpr size_t WPT_OFF  = WKVT_OFF + (size_t)768*1152*2;        // 1152*1152 bf16
constexpr size_t W1T_OFF  = WPT_OFF  + (size_t)1152*1152*2;       // 4608*1152 bf16
constexpr size_t W2T_OFF  = W1T_OFF  + (size_t)4608*1152*2;       // 1152*4608 bf16
constexpr size_t MOD_OFF  = W2T_OFF  + (size_t)1152*4608*2;       // 32*6912 f32
constexpr size_t QSC_OFF  = MOD_OFF  + (size_t)BB*MODW*4;         // 32*12 f32
constexpr size_t KSC_OFF  = QSC_OFF  + 1536;                      // 32*4 f32
constexpr size_t DYN_OFF  = KSC_OFF  + 512;                       // chunked scratch

static int pick_gn(int nb) {
    for (int g = 12; g >= 2; --g) if (nb % g == 0) return g;
    return 1;
}

extern "C" void kernel_launch(void* const* d_in, const int* in_sizes, int n_in,
                              void* d_out, int out_size, void* d_ws, size_t ws_size,
                              hipStream_t stream) {
    (void)in_sizes; (void)n_in; (void)out_size;

    const float* x       = (const float*)d_in[0];
    const float* cvec    = (const float*)d_in[1];
    const float* wq_w    = (const float*)d_in[2];
    const float* wq_b    = (const float*)d_in[3];
    const float* wkv_w   = (const float*)d_in[4];
    const float* wkv_b   = (const float*)d_in[5];
    const float* dwc_w   = (const float*)d_in[6];
    const float* dwc_b   = (const float*)d_in[7];
    const float* proj_w  = (const float*)d_in[8];
    const float* proj_b  = (const float*)d_in[9];
    const float* adaln_w = (const float*)d_in[10];
    const float* adaln_b = (const float*)d_in[11];
    const float* mlp_w1  = (const float*)d_in[12];
    const float* mlp_b1  = (const float*)d_in[13];
    const float* mlp_w2  = (const float*)d_in[14];
    const float* mlp_b2  = (const float*)d_in[15];

    // ---- adaptive chunk size: largest CB batches whose scratch fits ws_size ----
    int CB = 0;
    for (int cb = 32; cb >= 1; cb >>= 1) {
        size_t rows = (size_t)cb * 1024;
        size_t attn = rows * (1152*2 + 1152*4 + 768*4 + 384*2 + 1152*2)
                    + (size_t)cb * 4 * 9216 * 4;
        size_t mlp  = rows * (1152*2 + 4608*2);
        size_t need = DYN_OFF + (attn > mlp ? attn : mlp);
        if (need <= ws_size) { CB = cb; break; }
    }
    if (CB == 0) return;
    const size_t CROWS = (size_t)CB * 1024;

    char* ws = (char*)d_ws;
    unsigned short* WQT  = (unsigned short*)(ws + WQT_OFF);   // rows 0..1151 of merged [1920][1152]
    unsigned short* WKVT = (unsigned short*)(ws + WKVT_OFF);  // rows 1152..1919
    unsigned short* WPT  = (unsigned short*)(ws + WPT_OFF);
    unsigned short* W1T  = (unsigned short*)(ws + W1T_OFF);
    unsigned short* W2T  = (unsigned short*)(ws + W2T_OFF);
    float*          MODp = (float*)(ws + MOD_OFF);
    float*          QSC  = (float*)(ws + QSC_OFF);
    float*          KSC  = (float*)(ws + KSC_OFF);
    char* dyn = ws + DYN_OFF;
    unsigned short* XMc  = (unsigned short*)dyn;
    float*          QLc  = (float*)(dyn + CROWS * 1152 * 2);
    float*          KVLc = (float*)((char*)QLc + CROWS * 1152 * 4);
    float*          KVMc = (float*)((char*)KVLc + CROWS * 768 * 4);
    unsigned short* VDc  = (unsigned short*)((char*)KVMc + (size_t)CB * 4 * 9216 * 4);
    unsigned short* OBc  = (unsigned short*)((char*)VDc + CROWS * 384 * 2);
    unsigned short* XM2  = (unsigned short*)dyn;
    unsigned short* Hc   = (unsigned short*)(dyn + CROWS * 1152 * 2);
    float*          OUT  = (float*)d_out;

    dim3 tb(32, 8);
    k_transpose_bf16<<<dim3(36, 36),  tb, 0, stream>>>(wq_w,   WQT,  1152, 1152);
    k_transpose_bf16<<<dim3(36, 24),  tb, 0, stream>>>(wkv_w,  WKVT, 1152, 768);
    k_transpose_bf16<<<dim3(36, 36),  tb, 0, stream>>>(proj_w, WPT,  1152, 1152);
    k_transpose_bf16<<<dim3(36, 144), tb, 0, stream>>>(mlp_w1, W1T,  1152, 4608);
    k_transpose_bf16<<<dim3(144, 36), tb, 0, stream>>>(mlp_w2, W2T,  4608, 1152);

    k_mod<<<dim3(27, 4), 256, 0, stream>>>(cvec, adaln_w, adaln_b, MODp);

    const int MB = (int)(CROWS >> 7);      // 128-row M blocks per chunk
    const int GM = MB < 16 ? MB : 16;
    const int GN_QKV  = pick_gn(15);       // 5
    const int GN_PROJ = pick_gn(9);        // 9
    const int GN_MLP1 = pick_gn(36);       // 12
    const int GN_MLP2 = pick_gn(9);        // 9

    // --- attention branch, chunked over batches ---
    for (int b0 = 0; b0 < BB; b0 += CB) {
        const int r0 = b0 << 10;
        const float* xch = x + (size_t)r0 * HID;
        k_ln_mod<<<(int)CROWS, 256, 0, stream>>>(xch, MODp, 0, 1, XMc, r0);
        k_gemm_bt<3><<<15 * MB, 256, 0, stream>>>(XMc, WQT, wq_b, wkv_b, QLc, KVLc,
                                                  nullptr, nullptr, 1152, 1152, 0, MB, GM, GN_QKV);
        k_fnorms<<<CB * 16, 256, 0, stream>>>(QLc, KVLc, QSC, KSC, b0);
        k_dwconv<<<(int)(CROWS * 96 / 256), 256, 0, stream>>>(KVLc, dwc_w, dwc_b, VDc);
        k_kvmat<<<CB * 4, 256, 0, stream>>>(KVLc, KSC, KVMc, b0);
        k_ogemm<<<dim3(8, HEADS, CB), 256, 0, stream>>>(QLc, QSC, KVMc, VDc, OBc, b0);
        k_gemm_bt<2><<<9 * MB, 256, 0, stream>>>(OBc, WPT, proj_b, nullptr, OUT + (size_t)r0 * HID, nullptr,
                                                 xch, MODp + 2 * HID, 1152, 1152, r0, MB, GM, GN_PROJ);
    }

    // --- MLP branch, chunked over rows (d_out now holds x1 = x + gate*attn) ---
    for (int r0 = 0; r0 < ROWS; r0 += (int)CROWS) {
        float* x1ch = OUT + (size_t)r0 * HID;
        k_ln_mod<<<(int)CROWS, 256, 0, stream>>>(x1ch, MODp, 3, 4, XM2, r0);
        k_gemm_bt<1><<<36 * MB, 256, 0, stream>>>(XM2, W1T, mlp_b1, nullptr, Hc, nullptr,
                                                  nullptr, nullptr, 4608, 1152, 0, MB, GM, GN_MLP1);
        k_gemm_bt<2><<<9 * MB, 256, 0, stream>>>(Hc, W2T, mlp_b2, nullptr, x1ch, nullptr,
                                                 x1ch, MODp + 5 * HID, 1152, 4608, r0, MB, GM, GN_MLP2);
    }
}

// Round 6
// 2189.997 us; speedup vs baseline: 1.7010x; 1.0094x over previous
//
#include <hip/hip_runtime.h>
#include <hip/hip_bf16.h>
#include <cstdint>
#include <cstddef>

#define DEV __device__ __forceinline__

// ---------------- problem constants ----------------
constexpr int BB    = 32;
constexpr int SEQ   = 1024;
constexpr int HID   = 1152;
constexpr int HEADS = 12;
constexpr int KVH   = 4;
constexpr int HD    = 96;
constexpr int KVC   = 384;   // KVH*HD
constexpr int MLPD  = 4608;
constexpr int ROWS  = BB * SEQ;          // 32768
constexpr int MODW  = 6 * HID;           // 6912

typedef __attribute__((ext_vector_type(8))) short short8;
typedef __attribute__((ext_vector_type(4))) float f32x4;

// ---------------- helpers ----------------
DEV float bfu2f(unsigned short u) {
    unsigned v = ((unsigned)u) << 16;
    return __builtin_bit_cast(float, v);
}
DEV unsigned short f2bf16u(float f) {
    unsigned u = __builtin_bit_cast(unsigned, f);
    u += 0x7FFFu + ((u >> 16) & 1u);   // RNE
    return (unsigned short)(u >> 16);
}
DEV unsigned pack2(float a, float b) {
    return (unsigned)f2bf16u(a) | ((unsigned)f2bf16u(b) << 16);
}
DEV float gelu_tanh(float x) {
    float x3 = x * x * x;
    float t = tanhf(0.7978845608028654f * (x + 0.044715f * x3));
    return 0.5f * x * (1.f + t);
}

// async global->LDS, 16B per lane. LDS dest must be wave-uniform base (+lane*16).
DEV void gload16(const void* g, void* l) {
    __builtin_amdgcn_global_load_lds(
        (const __attribute__((address_space(1))) unsigned int*)g,
        (__attribute__((address_space(3))) unsigned int*)l,
        16, 0, 0);
}

// block reduce of two floats, blockDim.x == 256
DEV void block_reduce2(float& a, float& b) {
    #pragma unroll
    for (int off = 32; off > 0; off >>= 1) {
        a += __shfl_down(a, off, 64);
        b += __shfl_down(b, off, 64);
    }
    __shared__ float sa[4], sb[4];
    int w = threadIdx.x >> 6;
    if ((threadIdx.x & 63) == 0) { sa[w] = a; sb[w] = b; }
    __syncthreads();
    a = sa[0] + sa[1] + sa[2] + sa[3];
    b = sb[0] + sb[1] + sb[2] + sb[3];
    __syncthreads();
}

// ---------------- weight transpose + bf16 convert (+ zero-pad rows N..Npad) ----------------
__global__ void k_transpose_bf16(const float* __restrict__ in,
                                 unsigned short* __restrict__ out, int K, int N, int Npad) {
    __shared__ float tile[32][33];
    int kb = blockIdx.x * 32;
    int nb = blockIdx.y * 32;
    int tx = threadIdx.x, ty = threadIdx.y;   // (32, 8)
    #pragma unroll
    for (int j = 0; j < 4; j++) {
        int k = kb + ty + j * 8;
        tile[ty + j * 8][tx] = (k < K && nb + tx < N) ? in[(size_t)k * N + nb + tx] : 0.f;
    }
    __syncthreads();
    #pragma unroll
    for (int j = 0; j < 4; j++) {
        int n = nb + ty + j * 8;
        if (n < Npad && kb + tx < K)
            out[(size_t)n * K + kb + tx] = (n < N) ? f2bf16u(tile[tx][ty + j * 8]) : 0;
    }
}

// ---------------- adaLN: mod = silu(c) @ adaln_w + adaln_b ----------------
__global__ __launch_bounds__(256) void k_mod(const float* __restrict__ cvec,
                                             const float* __restrict__ w,
                                             const float* __restrict__ bias,
                                             float* __restrict__ mod) {
    const int col = blockIdx.x * 256 + threadIdx.x;
    const int bg = blockIdx.y * 8;
    __shared__ float sc[8][HID];
    for (int t = threadIdx.x; t < 8 * HID; t += 256) {
        int bb = t / HID, k = t % HID;
        float v = cvec[(bg + bb) * HID + k];
        sc[bb][k] = v / (1.f + __expf(-v));
    }
    __syncthreads();
    float acc[8];
    const float bv = bias[col];
    #pragma unroll
    for (int b = 0; b < 8; b++) acc[b] = bv;
    for (int k = 0; k < HID; k++) {
        float wv = w[(size_t)k * MODW + col];
        #pragma unroll
        for (int b = 0; b < 8; b++) acc[b] += sc[b][k] * wv;
    }
    #pragma unroll
    for (int b = 0; b < 8; b++) mod[(size_t)(bg + b) * MODW + col] = acc[b];
}

// ---------------- layernorm + modulate -> bf16 ----------------
__global__ __launch_bounds__(256) void k_ln_mod(const float* __restrict__ x,
                                                const float* __restrict__ mod,
                                                int shift_chunk, int scale_chunk,
                                                unsigned short* __restrict__ out,
                                                int r0) {
    const size_t row = blockIdx.x;
    const int b = (int)((r0 + row) >> 10);
    const float4* xr = (const float4*)(x + row * HID);
    const int t = threadIdx.x;
    float4 v0 = xr[t];
    float4 v1 = make_float4(0.f, 0.f, 0.f, 0.f);
    if (t < 32) v1 = xr[256 + t];
    float s  = v0.x + v0.y + v0.z + v0.w + v1.x + v1.y + v1.z + v1.w;
    float s2 = v0.x*v0.x + v0.y*v0.y + v0.z*v0.z + v0.w*v0.w
             + v1.x*v1.x + v1.y*v1.y + v1.z*v1.z + v1.w*v1.w;
    block_reduce2(s, s2);
    const float mean = s * (1.f / HID);
    float var = s2 * (1.f / HID) - mean * mean;
    const float rstd = rsqrtf(fmaxf(var, 0.f) + 1e-6f);
    const float* shiftp = mod + (size_t)b * MODW + shift_chunk * HID;
    const float* scalep = mod + (size_t)b * MODW + scale_chunk * HID;
    {
        float4 sc = *(const float4*)(scalep + 4 * t);
        float4 sh = *(const float4*)(shiftp + 4 * t);
        float y0 = ((v0.x - mean) * rstd) * (1.f + sc.x) + sh.x;
        float y1 = ((v0.y - mean) * rstd) * (1.f + sc.y) + sh.y;
        float y2 = ((v0.z - mean) * rstd) * (1.f + sc.z) + sh.z;
        float y3 = ((v0.w - mean) * rstd) * (1.f + sc.w) + sh.w;
        uint2 o; o.x = pack2(y0, y1); o.y = pack2(y2, y3);
        *(uint2*)(out + row * HID + 4 * t) = o;
    }
    if (t < 32) {
        int col = 1024 + 4 * t;
        float4 sc = *(const float4*)(scalep + col);
        float4 sh = *(const float4*)(shiftp + col);
        float y0 = ((v1.x - mean) * rstd) * (1.f + sc.x) + sh.x;
        float y1 = ((v1.y - mean) * rstd) * (1.f + sc.y) + sh.y;
        float y2 = ((v1.z - mean) * rstd) * (1.f + sc.z) + sh.z;
        float y3 = ((v1.w - mean) * rstd) * (1.f + sc.w) + sh.w;
        uint2 o; o.x = pack2(y0, y1); o.y = pack2(y2, y3);
        *(uint2*)(out + row * HID + col) = o;
    }
}

// ---------------- 256x256 8-phase bf16 MFMA GEMM (m201-style, counted vmcnt) ----------------
// C = A(M,K) * BT(Npad,K)^T + bias. 8 waves (2M x 4N), BK=64, LDS 128KB double-buffered.
// Per K-tile: 4 phases {12x ds_read | staged gload_lds | barrier | lgkmcnt | setprio+16 MFMA | barrier}.
// Tile t+1's 8 half-tile loads burst-issued in phases 0-1 of tile t; single counted
// s_waitcnt vmcnt(4) per K-tile at phase 0 (retires tile t, keeps t+1 A-loads in flight).
// LDS swizzle: slot s of row r holds k-group s^(r&7) (0 bank conflicts, verified r3-r5).
// EPI 1: bf16 = gelu(acc+bias)   EPI 2: fp32 = resid + gate*(acc+bias)
// EPI 3: split qkv: fcol<1152 -> QL(f32,stride 1152), 1152<=fcol<1920 -> KVL(f32,stride 768)
template <int EPI>
__global__ __launch_bounds__(512, 2) void k_gemm256(
        const unsigned short* __restrict__ A, const unsigned short* __restrict__ BT,
        const float* __restrict__ bias, const float* __restrict__ bias2,
        void* __restrict__ outp, float* __restrict__ out2,
        const float* __restrict__ resid, const float* __restrict__ gate,
        int Np, int NREAL, int K, int r0, int MB256, int GM, int GN) {
    __shared__ __align__(128) char L[131072];   // A: [0,64K) B: [64K,128K); each: 2 buf x 2 half x [128][64]bf16
    const int tid  = threadIdx.x;
    const int lane = tid & 63;
    const int wave = tid >> 6;          // 0..7
    const int wm   = wave >> 2;         // 0..1  (M half)
    const int wn   = wave & 3;          // 0..3  (N quarter)
    const int bh   = wn >> 1;           // B half this wave reads

    // ---- supertile + bijective XCD chunk swizzle ----
    const int P  = GM * GN;
    const int s  = blockIdx.x / P;
    const int rr = blockIdx.x % P;
    const int q8 = P >> 3, r8 = P & 7;
    const int xcd = rr & 7, off8 = rr >> 3;
    const int rw  = (xcd < r8 ? xcd * (q8 + 1) : r8 * (q8 + 1) + (xcd - r8) * q8) + off8;
    const int mloc = rw / GN, nloc = rw % GN;
    const int smCount = MB256 / GM;
    const int sm = s % smCount, sn = s / smCount;
    const int m0 = (sm * GM + mloc) << 8;
    const int n0 = (sn * GN + nloc) << 8;

    // ---- staging source pointers (per thread): piece s4 = half*2 + instr ----
    const int srow = tid >> 3;                       // 0..63
    const int kg   = (tid & 7) ^ (srow & 7);         // source-swizzled k-group
    const unsigned short* pa[4];
    const unsigned short* pb[4];
    #pragma unroll
    for (int s4 = 0; s4 < 4; ++s4) {
        const int h = s4 >> 1, i = s4 & 1;
        pa[s4] = A  + (size_t)(m0 + h * 128 + i * 64 + srow) * K + kg * 8;
        pb[s4] = BT + (size_t)(n0 + h * 128 + i * 64 + srow) * K + kg * 8;
    }
    const int dwo = wave * 1024;   // wave-uniform LDS sub-offset within an 8KB instr block

    // ---- fragment read offsets ----
    const int lo = lane & 15, hi = lane >> 4;
    const int swz = (hi ^ (lo & 7)) << 4;
    int aoff[8], boff[4];
    #pragma unroll
    for (int i = 0; i < 8; ++i) aoff[i] = (i * 16 + lo) * 128 + swz;
    #pragma unroll
    for (int j = 0; j < 4; ++j) boff[j] = ((wn & 1) * 64 + j * 16 + lo) * 128 + swz;

    f32x4 acc[8][4];
    #pragma unroll
    for (int i = 0; i < 8; ++i)
        #pragma unroll
        for (int j = 0; j < 4; ++j)
            acc[i][j] = (f32x4){0.f, 0.f, 0.f, 0.f};

    const int NK = K >> 6;

    // prologue: stage tile 0 into buf 0 (8 loads/wave)
    #pragma unroll
    for (int s4 = 0; s4 < 4; ++s4) {
        gload16(pa[s4], L + (s4 >> 1) * 16384 + (s4 & 1) * 8192 + dwo);
        gload16(pb[s4], L + 65536 + (s4 >> 1) * 16384 + (s4 & 1) * 8192 + dwo);
    }

    for (int kt = 0; kt < NK; ++kt) {
        const int c  = kt & 1;
        const int cn = c ^ 1;
        const char* Ab = L + c * 32768 + wm * 16384;
        const char* Bb = L + 65536 + c * 32768 + bh * 16384;
        const size_t koff = (size_t)(kt + 1) * 64;
        const bool more = (kt + 1 < NK);
        #pragma unroll
        for (int p = 0; p < 4; ++p) {
            const int qm = p & 1, qn = p >> 1;
            if (p == 0) {
                if (more) {
                    #pragma unroll
                    for (int s4 = 0; s4 < 4; ++s4)
                        gload16(pa[s4] + koff, L + cn * 32768 + (s4 >> 1) * 16384 + (s4 & 1) * 8192 + dwo);
                    asm volatile("s_waitcnt vmcnt(4)" ::: "memory");
                } else {
                    asm volatile("s_waitcnt vmcnt(0)" ::: "memory");
                }
                __builtin_amdgcn_s_barrier();
            }
            short8 av[4][2], bv[2][2];
            #pragma unroll
            for (int j = 0; j < 2; ++j)
                #pragma unroll
                for (int kk = 0; kk < 2; ++kk)
                    bv[j][kk] = *(const short8*)(Bb + (boff[qn * 2 + j] ^ (kk << 6)));
            #pragma unroll
            for (int i = 0; i < 4; ++i)
                #pragma unroll
                for (int kk = 0; kk < 2; ++kk)
                    av[i][kk] = *(const short8*)(Ab + (aoff[qm * 4 + i] ^ (kk << 6)));
            if (p == 1 && more) {
                #pragma unroll
                for (int s4 = 0; s4 < 4; ++s4)
                    gload16(pb[s4] + koff, L + 65536 + cn * 32768 + (s4 >> 1) * 16384 + (s4 & 1) * 8192 + dwo);
            }
            if (p != 0) __builtin_amdgcn_s_barrier();
            asm volatile("s_waitcnt lgkmcnt(0)" ::: "memory");
            __builtin_amdgcn_s_setprio(1);
            #pragma unroll
            for (int i = 0; i < 4; ++i)
                #pragma unroll
                for (int j = 0; j < 2; ++j)
                    #pragma unroll
                    for (int kk = 0; kk < 2; ++kk)
                        acc[qm * 4 + i][qn * 2 + j] =
                            __builtin_amdgcn_mfma_f32_16x16x32_bf16(av[i][kk], bv[j][kk],
                                                                    acc[qm * 4 + i][qn * 2 + j], 0, 0, 0);
            __builtin_amdgcn_s_setprio(0);
            __builtin_amdgcn_s_barrier();
        }
    }

    // ---- epilogue. C/D layout: col = lane&15, row = 4*(lane>>4)+reg ----
    const int c_l = lo;
    const int r_l = hi << 2;
    #pragma unroll
    for (int j4 = 0; j4 < 4; ++j4) {
        const int fcol = n0 + wn * 64 + j4 * 16 + c_l;
        const bool colok = fcol < NREAL;
        float bvv = 0.f;
        if (colok) {
            if constexpr (EPI == 3) bvv = (fcol < HID) ? bias[fcol] : bias2[fcol - HID];
            else                    bvv = bias[fcol];
        }
        #pragma unroll
        for (int i8 = 0; i8 < 8; ++i8) {
            const int frow = m0 + wm * 128 + i8 * 16 + r_l;
            #pragma unroll
            for (int r = 0; r < 4; ++r) {
                if (!colok) continue;
                float v = acc[i8][j4][r] + bvv;
                if constexpr (EPI == 1) {
                    ((unsigned short*)outp)[(size_t)(frow + r) * Np + fcol] = f2bf16u(gelu_tanh(v));
                } else if constexpr (EPI == 2) {
                    const size_t off = (size_t)(frow + r) * Np + fcol;
                    const int bb = (r0 + frow + r) >> 10;
                    ((float*)outp)[off] = resid[off] + gate[(size_t)bb * MODW + fcol] * v;
                } else {  // EPI 3
                    if (fcol < HID) ((float*)outp)[(size_t)(frow + r) * HID + fcol] = v;
                    else            out2[(size_t)(frow + r) * (2 * KVC) + (fcol - HID)] = v;
                }
            }
        }
    }
}

// ---------------- focused() norm scales for q (12 heads) and k (4 heads) ----------------
__global__ __launch_bounds__(256) void k_fnorms(const float* __restrict__ ql,
                                                const float* __restrict__ kvl,
                                                float* __restrict__ qscale,
                                                float* __restrict__ kscale,
                                                int b0) {
    const int b = blockIdx.x >> 4, hh = blockIdx.x & 15;
    const float* base;
    int stride;
    if (hh < HEADS) { base = ql  + (size_t)b * SEQ * HID + hh * HD;           stride = HID; }
    else            { base = kvl + (size_t)b * SEQ * (2*KVC) + (hh-HEADS)*HD; stride = 2*KVC; }
    float s2 = 0.f, s6 = 0.f;
    for (int i = threadIdx.x; i < SEQ * (HD / 4); i += 256) {
        int n = i / 24, dq = i % 24;
        float4 v = *(const float4*)(base + (size_t)n * stride + dq * 4);
        float a;
        a = fmaxf(v.x, 0.f); { float a2 = a*a; s2 += a2; s6 += a2*a2*a2; }
        a = fmaxf(v.y, 0.f); { float a2 = a*a; s2 += a2; s6 += a2*a2*a2; }
        a = fmaxf(v.z, 0.f); { float a2 = a*a; s2 += a2; s6 += a2*a2*a2; }
        a = fmaxf(v.w, 0.f); { float a2 = a*a; s2 += a2; s6 += a2*a2*a2; }
    }
    block_reduce2(s2, s6);
    if (threadIdx.x == 0) {
        float an  = sqrtf(s2);
        float apn = (s6 == 0.f) ? 1e-12f : sqrtf(s6);
        float sc = an / apn;
        if (hh < HEADS) qscale[(b0 + b) * HEADS + hh] = sc;
        else            kscale[(b0 + b) * KVH + (hh - HEADS)] = sc;
    }
}

// ---------------- depthwise 3x3 conv: 4 channels/thread, float4 loads ----------------
__global__ __launch_bounds__(256) void k_dwconv(const float* __restrict__ kvl,
                                                const float* __restrict__ w,
                                                const float* __restrict__ bias,
                                                unsigned short* __restrict__ vd) {
    const int idx = blockIdx.x * 256 + threadIdx.x;   // < CROWS*96
    const int c4 = idx % 96;
    const int bn = idx / 96;
    const int n = bn & 1023;
    const int b = bn >> 10;
    const int y = n >> 5, xx = n & 31;
    float4 acc = *(const float4*)(bias + c4 * 4);
    #pragma unroll
    for (int dy = -1; dy <= 1; dy++) {
        const int yy = y + dy;
        if ((unsigned)yy > 31u) continue;
        #pragma unroll
        for (int dx = -1; dx <= 1; dx++) {
            const int xc = xx + dx;
            if ((unsigned)xc > 31u) continue;
            float4 v = *(const float4*)(kvl + ((size_t)b * SEQ + yy * 32 + xc) * (2*KVC) + KVC + c4 * 4);
            const int t = (dy + 1) * 3 + (dx + 1);
            acc.x += w[(c4 * 4 + 0) * 9 + t] * v.x;
            acc.y += w[(c4 * 4 + 1) * 9 + t] * v.y;
            acc.z += w[(c4 * 4 + 2) * 9 + t] * v.z;
            acc.w += w[(c4 * 4 + 3) * 9 + t] * v.w;
        }
    }
    uint2 o; o.x = pack2(acc.x, acc.y); o.y = pack2(acc.z, acc.w);
    *(uint2*)(vd + (size_t)idx * 4) = o;
}

// ---------------- kvmat = focused(k)^T @ v  (per local b, kv-head: 96x96) ----------------
__global__ __launch_bounds__(256) void k_kvmat(const float* __restrict__ kvl,
                                               const float* __restrict__ kscale,
                                               float* __restrict__ kvmat,
                                               int b0) {
    const int b = blockIdx.x >> 2, h = blockIdx.x & 3;
    const float sc = kscale[(b0 + b) * KVH + h];
    __shared__ float Ks[16][96], Vs[16][96];
    float acc[6][6];
    #pragma unroll
    for (int i = 0; i < 6; i++)
        #pragma unroll
        for (int j = 0; j < 6; j++) acc[i][j] = 0.f;
    const int ti = threadIdx.x >> 4, tj = threadIdx.x & 15;
    const float* kbase = kvl + (size_t)b * SEQ * (2*KVC) + h * HD;
    const float* vbase = kbase + KVC;
    for (int n0 = 0; n0 < SEQ; n0 += 16) {
        __syncthreads();
        for (int i = threadIdx.x; i < 16 * 96; i += 256) {
            int nn = i / 96, d = i % 96;
            float kv_ = kbase[(size_t)(n0 + nn) * (2*KVC) + d];
            float r = fmaxf(kv_, 0.f);
            Ks[nn][d] = sc * r * r * r;
            Vs[nn][d] = vbase[(size_t)(n0 + nn) * (2*KVC) + d];
        }
        __syncthreads();
        for (int nn = 0; nn < 16; nn++) {
            float av[6], bv[6];
            #pragma unroll
            for (int i = 0; i < 6; i++) av[i] = Ks[nn][ti * 6 + i];
            #pragma unroll
            for (int j = 0; j < 6; j++) bv[j] = Vs[nn][tj * 6 + j];
            #pragma unroll
            for (int i = 0; i < 6; i++)
                #pragma unroll
                for (int j = 0; j < 6; j++) acc[i][j] += av[i] * bv[j];
        }
    }
    float* out = kvmat + (size_t)(b * KVH + h) * 96 * 96;
    #pragma unroll
    for (int i = 0; i < 6; i++)
        #pragma unroll
        for (int j = 0; j < 6; j++)
            out[(size_t)(ti * 6 + i) * 96 + tj * 6 + j] = acc[i][j];
}

// ---------------- o = focused(q) @ kvmat[h%4] + vd[h%4], out bf16 chunk-local ----------------
__global__ __launch_bounds__(256) void k_ogemm(const float* __restrict__ ql,
                                               const float* __restrict__ qscale,
                                               const float* __restrict__ kvmat,
                                               const unsigned short* __restrict__ vd,
                                               unsigned short* __restrict__ obuf,
                                               int b0) {
    const int rc = blockIdx.x;   // 0..7 row chunks of 128
    const int h  = blockIdx.y;   // 0..11
    const int b  = blockIdx.z;   // local batch
    const int kvh = h & 3;
    __shared__ float Ms[96][96];
    for (int i = threadIdx.x; i < 96 * 96; i += 256)
        Ms[i / 96][i % 96] = kvmat[(size_t)(b * KVH + kvh) * 9216 + i];
    const float qs = qscale[(b0 + b) * HEADS + h];
    __syncthreads();
    const int rowg = threadIdx.x >> 3;  // 0..31 (x4 rows)
    const int colg = threadIdx.x & 7;   // 0..7  (x12 cols)
    const int n_base = rc * 128 + rowg * 4;
    const float* qb = ql + ((size_t)(b * SEQ + n_base)) * HID + h * HD;
    float acc[4][12];
    #pragma unroll
    for (int r = 0; r < 4; r++)
        #pragma unroll
        for (int j = 0; j < 12; j++) acc[r][j] = 0.f;
    for (int k0 = 0; k0 < 96; k0 += 4) {
        float q_[4][4];
        #pragma unroll
        for (int r = 0; r < 4; r++) {
            float4 t = *(const float4*)(qb + (size_t)r * HID + k0);
            float a;
            a = fmaxf(t.x, 0.f); q_[r][0] = qs * a * a * a;
            a = fmaxf(t.y, 0.f); q_[r][1] = qs * a * a * a;
            a = fmaxf(t.z, 0.f); q_[r][2] = qs * a * a * a;
            a = fmaxf(t.w, 0.f); q_[r][3] = qs * a * a * a;
        }
        #pragma unroll
        for (int kk = 0; kk < 4; kk++) {
            float bv[12];
            #pragma unroll
            for (int j = 0; j < 12; j += 4) {
                float4 t = *(const float4*)&Ms[k0 + kk][colg * 12 + j];
                bv[j] = t.x; bv[j+1] = t.y; bv[j+2] = t.z; bv[j+3] = t.w;
            }
            #pragma unroll
            for (int r = 0; r < 4; r++)
                #pragma unroll
                for (int j = 0; j < 12; j++) acc[r][j] += q_[r][kk] * bv[j];
        }
    }
    const unsigned short* vdb = vd + ((size_t)(b * SEQ + n_base)) * KVC + kvh * HD + colg * 12;
    unsigned short* ob = obuf + ((size_t)(b * SEQ + n_base)) * HID + h * HD + colg * 12;
    for (int r = 0; r < 4; r++)
        for (int j = 0; j < 12; j++) {
            float v = acc[r][j] + bfu2f(vdb[(size_t)r * KVC + j]);
            ob[(size_t)r * HID + j] = f2bf16u(v);
        }
}

// ---------------- fixed workspace layout (weights padded to multiples of 256 rows) ----------------
constexpr size_t WQKV_OFF = 0;                                    // [2048][1152] bf16 (q rows 0-1151, kv 1152-1919, pad)
constexpr size_t WPT_OFF  = WQKV_OFF + (size_t)2048*1152*2;       // [1280][1152] bf16
constexpr size_t W1T_OFF  = WPT_OFF  + (size_t)1280*1152*2;       // [4608][1152] bf16
constexpr size_t W2T_OFF  = W1T_OFF  + (size_t)4608*1152*2;       // [1280][4608] bf16
constexpr size_t MOD_OFF  = W2T_OFF  + (size_t)1280*4608*2;       // 32*6912 f32
constexpr size_t QSC_OFF  = MOD_OFF  + (size_t)BB*MODW*4;         // 32*12 f32
constexpr size_t KSC_OFF  = QSC_OFF  + 1536;                      // 32*4 f32
constexpr size_t DYN_OFF  = KSC_OFF  + 512;                       // chunked scratch

extern "C" void kernel_launch(void* const* d_in, const int* in_sizes, int n_in,
                              void* d_out, int out_size, void* d_ws, size_t ws_size,
                              hipStream_t stream) {
    (void)in_sizes; (void)n_in; (void)out_size;

    const float* x       = (const float*)d_in[0];
    const float* cvec    = (const float*)d_in[1];
    const float* wq_w    = (const float*)d_in[2];
    const float* wq_b    = (const float*)d_in[3];
    const float* wkv_w   = (const float*)d_in[4];
    const float* wkv_b   = (const float*)d_in[5];
    const float* dwc_w   = (const float*)d_in[6];
    const float* dwc_b   = (const float*)d_in[7];
    const float* proj_w  = (const float*)d_in[8];
    const float* proj_b  = (const float*)d_in[9];
    const float* adaln_w = (const float*)d_in[10];
    const float* adaln_b = (const float*)d_in[11];
    const float* mlp_w1  = (const float*)d_in[12];
    const float* mlp_b1  = (const float*)d_in[13];
    const float* mlp_w2  = (const float*)d_in[14];
    const float* mlp_b2  = (const float*)d_in[15];

    // ---- adaptive chunk size: largest CB batches whose scratch fits ws_size ----
    int CB = 0;
    for (int cb = 32; cb >= 1; cb >>= 1) {
        size_t rows = (size_t)cb * 1024;
        size_t attn = rows * (1152*2 + 1152*4 + 768*4 + 384*2 + 1152*2)
                    + (size_t)cb * 4 * 9216 * 4;
        size_t mlp  = rows * (1152*2 + 4608*2);
        size_t need = DYN_OFF + (attn > mlp ? attn : mlp);
        if (need <= ws_size) { CB = cb; break; }
    }
    if (CB == 0) return;
    const size_t CROWS = (size_t)CB * 1024;

    char* ws = (char*)d_ws;
    unsigned short* WQKV = (unsigned short*)(ws + WQKV_OFF);
    unsigned short* WPT  = (unsigned short*)(ws + WPT_OFF);
    unsigned short* W1T  = (unsigned short*)(ws + W1T_OFF);
    unsigned short* W2T  = (unsigned short*)(ws + W2T_OFF);
    float*          MODp = (float*)(ws + MOD_OFF);
    float*          QSC  = (float*)(ws + QSC_OFF);
    float*          KSC  = (float*)(ws + KSC_OFF);
    char* dyn = ws + DYN_OFF;
    unsigned short* XMc  = (unsigned short*)dyn;
    float*          QLc  = (float*)(dyn + CROWS * 1152 * 2);
    float*          KVLc = (float*)((char*)QLc + CROWS * 1152 * 4);
    float*          KVMc = (float*)((char*)KVLc + CROWS * 768 * 4);
    unsigned short* VDc  = (unsigned short*)((char*)KVMc + (size_t)CB * 4 * 9216 * 4);
    unsigned short* OBc  = (unsigned short*)((char*)VDc + CROWS * 384 * 2);
    unsigned short* XM2  = (unsigned short*)dyn;
    unsigned short* Hc   = (unsigned short*)(dyn + CROWS * 1152 * 2);
    float*          OUT  = (float*)d_out;

    dim3 tb(32, 8);
    k_transpose_bf16<<<dim3(36, 36),  tb, 0, stream>>>(wq_w,   WQKV,             1152, 1152, 1152);
    k_transpose_bf16<<<dim3(36, 28),  tb, 0, stream>>>(wkv_w,  WQKV + 1152*1152, 1152, 768,  896);
    k_transpose_bf16<<<dim3(36, 40),  tb, 0, stream>>>(proj_w, WPT,              1152, 1152, 1280);
    k_transpose_bf16<<<dim3(36, 144), tb, 0, stream>>>(mlp_w1, W1T,              1152, 4608, 4608);
    k_transpose_bf16<<<dim3(144, 40), tb, 0, stream>>>(mlp_w2, W2T,              4608, 1152, 1280);

    k_mod<<<dim3(27, 4), 256, 0, stream>>>(cvec, adaln_w, adaln_b, MODp);

    const int MB256 = (int)(CROWS >> 8);        // 256-row M blocks per chunk
    const int GM = MB256 < 16 ? MB256 : 16;

    // --- attention branch, chunked over batches ---
    for (int b0 = 0; b0 < BB; b0 += CB) {
        const int r0 = b0 << 10;
        const float* xch = x + (size_t)r0 * HID;
        k_ln_mod<<<(int)CROWS, 256, 0, stream>>>(xch, MODp, 0, 1, XMc, r0);
        k_gemm256<3><<<8 * MB256, 512, 0, stream>>>(XMc, WQKV, wq_b, wkv_b, QLc, KVLc,
                                                    nullptr, nullptr, 0, 1920, 1152, 0, MB256, GM, 4);
        k_fnorms<<<CB * 16, 256, 0, stream>>>(QLc, KVLc, QSC, KSC, b0);
        k_dwconv<<<(int)(CROWS * 96 / 256), 256, 0, stream>>>(KVLc, dwc_w, dwc_b, VDc);
        k_kvmat<<<CB * 4, 256, 0, stream>>>(KVLc, KSC, KVMc, b0);
        k_ogemm<<<dim3(8, HEADS, CB), 256, 0, stream>>>(QLc, QSC, KVMc, VDc, OBc, b0);
        k_gemm256<2><<<5 * MB256, 512, 0, stream>>>(OBc, WPT, proj_b, nullptr, OUT + (size_t)r0 * HID, nullptr,
                                                    xch, MODp + 2 * HID, 1152, 1152, 1152, r0, MB256, GM, 5);
    }

    // --- MLP branch, chunked over rows (d_out now holds x1 = x + gate*attn) ---
    for (int r0 = 0; r0 < ROWS; r0 += (int)CROWS) {
        float* x1ch = OUT + (size_t)r0 * HID;
        k_ln_mod<<<(int)CROWS, 256, 0, stream>>>(x1ch, MODp, 3, 4, XM2, r0);
        k_gemm256<1><<<18 * MB256, 512, 0, stream>>>(XM2, W1T, mlp_b1, nullptr, Hc, nullptr,
                                                     nullptr, nullptr, 4608, 4608, 1152, 0, MB256, GM, 6);
        k_gemm256<2><<<5 * MB256, 512, 0, stream>>>(Hc, W2T, mlp_b2, nullptr, x1ch, nullptr,
                                                    x1ch, MODp + 5 * HID, 1152, 1152, 4608, r0, MB256, GM, 5);
    }
}

// Round 7
// 1994.604 us; speedup vs baseline: 1.8676x; 1.0980x over previous
//
#include <hip/hip_runtime.h>
#include <hip/hip_bf16.h>
#include <cstdint>
#include <cstddef>

#define DEV __device__ __forceinline__

// ---------------- problem constants ----------------
constexpr int BB    = 32;
constexpr int SEQ   = 1024;
constexpr int HID   = 1152;
constexpr int HEADS = 12;
constexpr int KVH   = 4;
constexpr int HD    = 96;
constexpr int KVC   = 384;   // KVH*HD
constexpr int MLPD  = 4608;
constexpr int ROWS  = BB * SEQ;          // 32768
constexpr int MODW  = 6 * HID;           // 6912

typedef __attribute__((ext_vector_type(8))) short short8;
typedef __attribute__((ext_vector_type(4))) float f32x4;

// ---------------- helpers ----------------
DEV float bfu2f(unsigned short u) {
    unsigned v = ((unsigned)u) << 16;
    return __builtin_bit_cast(float, v);
}
DEV unsigned short f2bf16u(float f) {
    unsigned u = __builtin_bit_cast(unsigned, f);
    u += 0x7FFFu + ((u >> 16) & 1u);   // RNE
    return (unsigned short)(u >> 16);
}
DEV unsigned pack2(float a, float b) {
    return (unsigned)f2bf16u(a) | ((unsigned)f2bf16u(b) << 16);
}
DEV float gelu_tanh(float x) {
    float x3 = x * x * x;
    float t = tanhf(0.7978845608028654f * (x + 0.044715f * x3));
    return 0.5f * x * (1.f + t);
}

// async global->LDS, 16B per lane. LDS dest must be wave-uniform base (+lane*16).
DEV void gload16(const void* g, void* l) {
    __builtin_amdgcn_global_load_lds(
        (const __attribute__((address_space(1))) unsigned int*)g,
        (__attribute__((address_space(3))) unsigned int*)l,
        16, 0, 0);
}

// block reduce of two floats, blockDim.x == 256
DEV void block_reduce2(float& a, float& b) {
    #pragma unroll
    for (int off = 32; off > 0; off >>= 1) {
        a += __shfl_down(a, off, 64);
        b += __shfl_down(b, off, 64);
    }
    __shared__ float sa[4], sb[4];
    int w = threadIdx.x >> 6;
    if ((threadIdx.x & 63) == 0) { sa[w] = a; sb[w] = b; }
    __syncthreads();
    a = sa[0] + sa[1] + sa[2] + sa[3];
    b = sb[0] + sb[1] + sb[2] + sb[3];
    __syncthreads();
}

// ---------------- weight transpose + bf16 convert ----------------
__global__ void k_transpose_bf16(const float* __restrict__ in,
                                 unsigned short* __restrict__ out, int K, int N) {
    __shared__ float tile[32][33];
    int kb = blockIdx.x * 32;
    int nb = blockIdx.y * 32;
    int tx = threadIdx.x, ty = threadIdx.y;   // (32, 8)
    #pragma unroll
    for (int j = 0; j < 4; j++) {
        int k = kb + ty + j * 8;
        tile[ty + j * 8][tx] = (k < K && nb + tx < N) ? in[(size_t)k * N + nb + tx] : 0.f;
    }
    __syncthreads();
    #pragma unroll
    for (int j = 0; j < 4; j++) {
        int n = nb + ty + j * 8;
        if (n < N && kb + tx < K)
            out[(size_t)n * K + kb + tx] = f2bf16u(tile[tx][ty + j * 8]);
    }
}

// ---------------- adaLN: mod = silu(c) @ adaln_w + adaln_b ----------------
__global__ __launch_bounds__(256) void k_mod(const float* __restrict__ cvec,
                                             const float* __restrict__ w,
                                             const float* __restrict__ bias,
                                             float* __restrict__ mod) {
    const int col = blockIdx.x * 256 + threadIdx.x;
    const int bg = blockIdx.y * 8;
    __shared__ float sc[8][HID];
    for (int t = threadIdx.x; t < 8 * HID; t += 256) {
        int bb = t / HID, k = t % HID;
        float v = cvec[(bg + bb) * HID + k];
        sc[bb][k] = v / (1.f + __expf(-v));
    }
    __syncthreads();
    float acc[8];
    const float bv = bias[col];
    #pragma unroll
    for (int b = 0; b < 8; b++) acc[b] = bv;
    for (int k = 0; k < HID; k++) {
        float wv = w[(size_t)k * MODW + col];
        #pragma unroll
        for (int b = 0; b < 8; b++) acc[b] += sc[b][k] * wv;
    }
    #pragma unroll
    for (int b = 0; b < 8; b++) mod[(size_t)(bg + b) * MODW + col] = acc[b];
}

// ---------------- layernorm + modulate -> bf16 ----------------
__global__ __launch_bounds__(256) void k_ln_mod(const float* __restrict__ x,
                                                const float* __restrict__ mod,
                                                int shift_chunk, int scale_chunk,
                                                unsigned short* __restrict__ out,
                                                int r0) {
    const size_t row = blockIdx.x;
    const int b = (int)((r0 + row) >> 10);
    const float4* xr = (const float4*)(x + row * HID);
    const int t = threadIdx.x;
    float4 v0 = xr[t];
    float4 v1 = make_float4(0.f, 0.f, 0.f, 0.f);
    if (t < 32) v1 = xr[256 + t];
    float s  = v0.x + v0.y + v0.z + v0.w + v1.x + v1.y + v1.z + v1.w;
    float s2 = v0.x*v0.x + v0.y*v0.y + v0.z*v0.z + v0.w*v0.w
             + v1.x*v1.x + v1.y*v1.y + v1.z*v1.z + v1.w*v1.w;
    block_reduce2(s, s2);
    const float mean = s * (1.f / HID);
    float var = s2 * (1.f / HID) - mean * mean;
    const float rstd = rsqrtf(fmaxf(var, 0.f) + 1e-6f);
    const float* shiftp = mod + (size_t)b * MODW + shift_chunk * HID;
    const float* scalep = mod + (size_t)b * MODW + scale_chunk * HID;
    {
        float4 sc = *(const float4*)(scalep + 4 * t);
        float4 sh = *(const float4*)(shiftp + 4 * t);
        float y0 = ((v0.x - mean) * rstd) * (1.f + sc.x) + sh.x;
        float y1 = ((v0.y - mean) * rstd) * (1.f + sc.y) + sh.y;
        float y2 = ((v0.z - mean) * rstd) * (1.f + sc.z) + sh.z;
        float y3 = ((v0.w - mean) * rstd) * (1.f + sc.w) + sh.w;
        uint2 o; o.x = pack2(y0, y1); o.y = pack2(y2, y3);
        *(uint2*)(out + row * HID + 4 * t) = o;
    }
    if (t < 32) {
        int col = 1024 + 4 * t;
        float4 sc = *(const float4*)(scalep + col);
        float4 sh = *(const float4*)(shiftp + col);
        float y0 = ((v1.x - mean) * rstd) * (1.f + sc.x) + sh.x;
        float y1 = ((v1.y - mean) * rstd) * (1.f + sc.y) + sh.y;
        float y2 = ((v1.z - mean) * rstd) * (1.f + sc.z) + sh.z;
        float y3 = ((v1.w - mean) * rstd) * (1.f + sc.w) + sh.w;
        uint2 o; o.x = pack2(y0, y1); o.y = pack2(y2, y3);
        *(uint2*)(out + row * HID + col) = o;
    }
}

// ---------------- bf16 MFMA GEMM: C = A(M,K) * BT(N,K)^T + bias ----------------
// 128x128 tile, BK=64, global_load_lds staging, source-swizzled LDS (0 bank conflicts),
// 2D supertile (GM x GN) + m204 bijective XCD chunk swizzle for L2/L3 locality.
// __launch_bounds__(256,4): 64 VGPR + 64 AGPR = 128/wave exactly; (256,5) SPILLS (r4).
// EPI 1: out bf16 = gelu(acc + bias)
// EPI 2: out fp32 = resid + gate[b,col]*(acc + bias)   (b from global row r0+row)
// EPI 3: qkv split: fcol<1152 -> QL(bf16,stride 1152), else KVL(bf16,stride 768, bias2);
//        fused focused-norm sums (fp32 pre-rounding): q cols 0..1151, k cols 1152..1535.
template <int EPI>
__global__ __launch_bounds__(256, 4) void k_gemm_bt(
        const unsigned short* __restrict__ A, const unsigned short* __restrict__ BT,
        const float* __restrict__ bias, const float* __restrict__ bias2,
        void* __restrict__ outp, void* __restrict__ out2,
        const float* __restrict__ resid, const float* __restrict__ gate,
        float* __restrict__ qsn, float* __restrict__ ksn,
        int Np, int K, int r0, int MBk, int GM, int GN) {
    __shared__ __align__(16) char As[16384];
    __shared__ __align__(16) char Bs[16384];
    __shared__ float sb2[16], sb6[16];
    const int tid  = threadIdx.x;
    const int lane = tid & 63;
    const int wave = tid >> 6;
    const int wr = wave >> 1, wc = wave & 1;

    // ---- supertile + XCD-chunk block swizzle (bijective) ----
    const int P  = GM * GN;
    const int s  = blockIdx.x / P;
    const int rr = blockIdx.x % P;
    const int q8 = P >> 3, r8 = P & 7;
    const int xcd = rr & 7, off8 = rr >> 3;
    const int rw  = (xcd < r8 ? xcd * (q8 + 1) : r8 * (q8 + 1) + (xcd - r8) * q8) + off8;
    const int mloc = rw / GN, nloc = rw % GN;
    const int smCount = MBk / GM;
    const int sm = s % smCount, sn = s / smCount;
    const int m0 = (sm * GM + mloc) << 7;
    const int n0 = (sn * GN + nloc) << 7;

    // staging: wave w covers rows 32w..32w+31 (4 chunks of 8 rows = 1KB each).
    const int srow = lane >> 3;                 // 0..7
    const int kgrp = (lane & 7) ^ srow;         // swizzled k-group for this lane
    const unsigned short* aS = A  + (size_t)(m0 + 32 * wave + srow) * K + kgrp * 8;
    const unsigned short* bS = BT + (size_t)(n0 + 32 * wave + srow) * K + kgrp * 8;
    const size_t chunkK = (size_t)8 * K;        // 8 rows per chunk
    char* aD = As + wave * 4096;
    char* bD = Bs + wave * 4096;

    // fragment read offsets: byte = r*128 + ((kg ^ (r&7))<<4); kk=1 -> ^64
    const int hi = lane >> 4;
    const int lo = lane & 15;
    const int swz = ((hi ^ (lo & 7)) << 4);
    int aoff[4], boff[4];
    #pragma unroll
    for (int i = 0; i < 4; i++) {
        aoff[i] = (wr * 64 + i * 16 + lo) * 128 + swz;
        boff[i] = (wc * 64 + i * 16 + lo) * 128 + swz;
    }

    f32x4 acc[4][4];
    #pragma unroll
    for (int i = 0; i < 4; i++)
        #pragma unroll
        for (int j = 0; j < 4; j++)
            acc[i][j] = (f32x4){0.f, 0.f, 0.f, 0.f};

    if constexpr (EPI == 3) {
        if (tid < 16) { sb2[tid] = 0.f; sb6[tid] = 0.f; }
    }

    const int nk = K >> 6;
    for (int kt = 0; kt < nk; ++kt) {
        __syncthreads();
        #pragma unroll
        for (int j = 0; j < 4; j++) {
            gload16(aS + j * chunkK, aD + j * 1024);
            gload16(bS + j * chunkK, bD + j * 1024);
        }
        aS += 64; bS += 64;
        __syncthreads();
        #pragma unroll
        for (int kk = 0; kk < 2; kk++) {
            const int kx = kk << 6;
            short8 bfr[4];
            #pragma unroll
            for (int j = 0; j < 4; j++)
                bfr[j] = *(const short8*)(Bs + (boff[j] ^ kx));
            #pragma unroll
            for (int i = 0; i < 4; i++) {
                short8 af = *(const short8*)(As + (aoff[i] ^ kx));
                #pragma unroll
                for (int j = 0; j < 4; j++)
                    acc[i][j] = __builtin_amdgcn_mfma_f32_16x16x32_bf16(af, bfr[j], acc[i][j], 0, 0, 0);
            }
        }
    }

    // epilogue. C/D layout: col = lane&15, row = 4*(lane>>4)+reg
    const int c_l = lane & 15;
    const int r_l = (lane >> 4) << 2;
    #pragma unroll
    for (int j = 0; j < 4; j++) {
        const int fcol = n0 + wc * 64 + j * 16 + c_l;
        float bvv;
        if constexpr (EPI == 3) bvv = (fcol < HID) ? bias[fcol] : bias2[fcol - HID];
        else                    bvv = bias[fcol];
        float s2l = 0.f, s6l = 0.f;
        #pragma unroll
        for (int i = 0; i < 4; i++) {
            const int frow = m0 + wr * 64 + i * 16 + r_l;
            #pragma unroll
            for (int r = 0; r < 4; r++) {
                float v = acc[i][j][r] + bvv;
                if constexpr (EPI == 1) {
                    ((unsigned short*)outp)[(size_t)(frow + r) * Np + fcol] = f2bf16u(gelu_tanh(v));
                } else if constexpr (EPI == 2) {
                    const size_t off = (size_t)(frow + r) * Np + fcol;
                    const int bb = (r0 + frow + r) >> 10;
                    ((float*)outp)[off] = resid[off] + gate[(size_t)bb * MODW + fcol] * v;
                } else {  // EPI 3
                    unsigned short bf = f2bf16u(v);
                    if (fcol < HID) ((unsigned short*)outp)[(size_t)(frow + r) * HID + fcol] = bf;
                    else            ((unsigned short*)out2)[(size_t)(frow + r) * (2*KVC) + (fcol - HID)] = bf;
                    if (fcol < HID + KVC) {   // q or k column: accumulate focused-norm sums
                        float rv = fmaxf(v, 0.f);
                        float v2 = rv * rv;
                        s2l += v2;
                        s6l += v2 * v2 * v2;
                    }
                }
            }
        }
        if constexpr (EPI == 3) {
            if (fcol < HID + KVC) {
                s2l += __shfl_down(s2l, 32, 64); s2l += __shfl_down(s2l, 16, 64);
                s6l += __shfl_down(s6l, 32, 64); s6l += __shfl_down(s6l, 16, 64);
                if (lane < 16) {
                    const int slot = (fcol < HID) ? (fcol / 96) : (12 + (fcol - HID) / 96);
                    atomicAdd(&sb2[slot], s2l);
                    atomicAdd(&sb6[slot], s6l);
                }
            }
        }
    }
    if constexpr (EPI == 3) {
        __syncthreads();
        if (tid < 16) {
            const int b = (r0 + m0) >> 10;   // 128-row tile lies in a single batch
            if (tid < 12) {
                atomicAdd(&qsn[(b * HEADS + tid) * 2],     sb2[tid]);
                atomicAdd(&qsn[(b * HEADS + tid) * 2 + 1], sb6[tid]);
            } else {
                atomicAdd(&ksn[(b * KVH + tid - 12) * 2],     sb2[tid]);
                atomicAdd(&ksn[(b * KVH + tid - 12) * 2 + 1], sb6[tid]);
            }
        }
    }
}

// ---------------- finisher: norm sums -> scales (1 block, 512 threads) ----------------
__global__ void k_fin(const float* __restrict__ qsn, const float* __restrict__ ksn,
                      float* __restrict__ qsc, float* __restrict__ ksc) {
    const int t = threadIdx.x;
    if (t < BB * HEADS) {
        float s2 = qsn[t * 2], s6 = qsn[t * 2 + 1];
        float apn = (s6 == 0.f) ? 1e-12f : sqrtf(s6);
        qsc[t] = sqrtf(s2) / apn;
    } else if (t < BB * HEADS + BB * KVH) {
        int i = t - BB * HEADS;
        float s2 = ksn[i * 2], s6 = ksn[i * 2 + 1];
        float apn = (s6 == 0.f) ? 1e-12f : sqrtf(s6);
        ksc[i] = sqrtf(s2) / apn;
    }
}

// ---------------- depthwise 3x3 conv (bf16 in): 4 channels/thread ----------------
__global__ __launch_bounds__(256) void k_dwconv(const unsigned short* __restrict__ kvl,
                                                const float* __restrict__ w,
                                                const float* __restrict__ bias,
                                                unsigned short* __restrict__ vd) {
    const int idx = blockIdx.x * 256 + threadIdx.x;   // < CROWS*96
    const int c4 = idx % 96;
    const int bn = idx / 96;
    const int n = bn & 1023;
    const int b = bn >> 10;
    const int y = n >> 5, xx = n & 31;
    float4 acc = *(const float4*)(bias + c4 * 4);
    #pragma unroll
    for (int dy = -1; dy <= 1; dy++) {
        const int yy = y + dy;
        if ((unsigned)yy > 31u) continue;
        #pragma unroll
        for (int dx = -1; dx <= 1; dx++) {
            const int xc = xx + dx;
            if ((unsigned)xc > 31u) continue;
            uint2 u = *(const uint2*)(kvl + ((size_t)b * SEQ + yy * 32 + xc) * (2*KVC) + KVC + c4 * 4);
            const int t = (dy + 1) * 3 + (dx + 1);
            acc.x += w[(c4 * 4 + 0) * 9 + t] * bfu2f((unsigned short)(u.x & 0xffff));
            acc.y += w[(c4 * 4 + 1) * 9 + t] * bfu2f((unsigned short)(u.x >> 16));
            acc.z += w[(c4 * 4 + 2) * 9 + t] * bfu2f((unsigned short)(u.y & 0xffff));
            acc.w += w[(c4 * 4 + 3) * 9 + t] * bfu2f((unsigned short)(u.y >> 16));
        }
    }
    uint2 o; o.x = pack2(acc.x, acc.y); o.y = pack2(acc.z, acc.w);
    *(uint2*)(vd + (size_t)idx * 4) = o;
}

// ---------------- kvmat partials: relu(k)^3 ^T @ v over 128-row chunk ----------------
// grid: CB*4*8 blocks (bh = blockIdx>>3, chunk = blockIdx&7). No kscale here (applied in reduce).
__global__ __launch_bounds__(256) void k_kvpart(const unsigned short* __restrict__ kvl,
                                                float* __restrict__ kvmp) {
    const int chunk = blockIdx.x & 7;
    const int bh = blockIdx.x >> 3;
    const int b = bh >> 2, h = bh & 3;
    __shared__ float Ks[16][96], Vs[16][96];
    float acc[6][6];
    #pragma unroll
    for (int i = 0; i < 6; i++)
        #pragma unroll
        for (int j = 0; j < 6; j++) acc[i][j] = 0.f;
    const int ti = threadIdx.x >> 4, tj = threadIdx.x & 15;
    const unsigned short* kbase = kvl + ((size_t)b * SEQ + chunk * 128) * (2*KVC) + h * HD;
    for (int n0 = 0; n0 < 128; n0 += 16) {
        __syncthreads();
        for (int i = threadIdx.x; i < 16 * 96; i += 256) {
            int nn = i / 96, d = i % 96;
            float kv_ = bfu2f(kbase[(size_t)(n0 + nn) * (2*KVC) + d]);
            float r = fmaxf(kv_, 0.f);
            Ks[nn][d] = r * r * r;
            Vs[nn][d] = bfu2f(kbase[(size_t)(n0 + nn) * (2*KVC) + KVC + d]);
        }
        __syncthreads();
        for (int nn = 0; nn < 16; nn++) {
            float av[6], bv[6];
            #pragma unroll
            for (int i = 0; i < 6; i++) av[i] = Ks[nn][ti * 6 + i];
            #pragma unroll
            for (int j = 0; j < 6; j++) bv[j] = Vs[nn][tj * 6 + j];
            #pragma unroll
            for (int i = 0; i < 6; i++)
                #pragma unroll
                for (int j = 0; j < 6; j++) acc[i][j] += av[i] * bv[j];
        }
    }
    float* out = kvmp + ((size_t)bh * 8 + chunk) * 9216;
    #pragma unroll
    for (int i = 0; i < 6; i++)
        #pragma unroll
        for (int j = 0; j < 6; j++)
            out[(size_t)(ti * 6 + i) * 96 + tj * 6 + j] = acc[i][j];
}

// ---------------- kvmat reduce: sum 8 partials, apply kscale ----------------
__global__ __launch_bounds__(256) void k_kvred(const float* __restrict__ kvmp,
                                               const float* __restrict__ ksc,
                                               float* __restrict__ kvm, int b0) {
    const int idx = blockIdx.x * 256 + threadIdx.x;   // < CB*4*9216
    const int bh = idx / 9216;
    const int i  = idx % 9216;
    float s = 0.f;
    #pragma unroll
    for (int c = 0; c < 8; c++) s += kvmp[((size_t)bh * 8 + c) * 9216 + i];
    kvm[(size_t)idx] = s * ksc[(b0 + (bh >> 2)) * KVH + (bh & 3)];
}

// ---------------- o = focused(q) @ kvmat[h%4] + vd[h%4] (q bf16), out bf16 ----------------
__global__ __launch_bounds__(256) void k_ogemm(const unsigned short* __restrict__ ql,
                                               const float* __restrict__ qscale,
                                               const float* __restrict__ kvmat,
                                               const unsigned short* __restrict__ vd,
                                               unsigned short* __restrict__ obuf,
                                               int b0) {
    const int rc = blockIdx.x;   // 0..7 row chunks of 128
    const int h  = blockIdx.y;   // 0..11
    const int b  = blockIdx.z;   // local batch
    const int kvh = h & 3;
    __shared__ float Ms[96][96];
    for (int i = threadIdx.x; i < 96 * 96; i += 256)
        Ms[i / 96][i % 96] = kvmat[(size_t)(b * KVH + kvh) * 9216 + i];
    const float qs = qscale[(b0 + b) * HEADS + h];
    __syncthreads();
    const int rowg = threadIdx.x >> 3;  // 0..31 (x4 rows)
    const int colg = threadIdx.x & 7;   // 0..7  (x12 cols)
    const int n_base = rc * 128 + rowg * 4;
    const unsigned short* qb = ql + ((size_t)(b * SEQ + n_base)) * HID + h * HD;
    float acc[4][12];
    #pragma unroll
    for (int r = 0; r < 4; r++)
        #pragma unroll
        for (int j = 0; j < 12; j++) acc[r][j] = 0.f;
    for (int k0 = 0; k0 < 96; k0 += 8) {
        float q_[4][8];
        #pragma unroll
        for (int r = 0; r < 4; r++) {
            uint4 qu = *(const uint4*)(qb + (size_t)r * HID + k0);
            const unsigned short* qe = (const unsigned short*)&qu;
            #pragma unroll
            for (int e = 0; e < 8; e++) {
                float a = fmaxf(bfu2f(qe[e]), 0.f);
                q_[r][e] = qs * a * a * a;
            }
        }
        #pragma unroll
        for (int kk = 0; kk < 8; kk++) {
            float bv[12];
            #pragma unroll
            for (int j = 0; j < 12; j += 4) {
                float4 t = *(const float4*)&Ms[k0 + kk][colg * 12 + j];
                bv[j] = t.x; bv[j+1] = t.y; bv[j+2] = t.z; bv[j+3] = t.w;
            }
            #pragma unroll
            for (int r = 0; r < 4; r++)
                #pragma unroll
                for (int j = 0; j < 12; j++) acc[r][j] += q_[r][kk] * bv[j];
        }
    }
    const unsigned short* vdb = vd + ((size_t)(b * SEQ + n_base)) * KVC + kvh * HD + colg * 12;
    unsigned short* ob = obuf + ((size_t)(b * SEQ + n_base)) * HID + h * HD + colg * 12;
    for (int r = 0; r < 4; r++)
        for (int j = 0; j < 12; j++) {
            float v = acc[r][j] + bfu2f(vdb[(size_t)r * KVC + j]);
            ob[(size_t)r * HID + j] = f2bf16u(v);
        }
}

// ---------------- fixed workspace layout ----------------
constexpr size_t WQKV_OFF = 0;                                    // [1920][1152] bf16 (q rows 0-1151, kv 1152-1919)
constexpr size_t WPT_OFF  = WQKV_OFF + (size_t)1920*1152*2;       // [1152][1152] bf16
constexpr size_t W1T_OFF  = WPT_OFF  + (size_t)1152*1152*2;       // [4608][1152] bf16
constexpr size_t W2T_OFF  = W1T_OFF  + (size_t)4608*1152*2;       // [1152][4608] bf16
constexpr size_t MOD_OFF  = W2T_OFF  + (size_t)1152*4608*2;       // 32*6912 f32
constexpr size_t QSN_OFF  = MOD_OFF  + (size_t)BB*MODW*4;         // 32*12*2 f32 (s2,s6)
constexpr size_t KSN_OFF  = QSN_OFF  + (size_t)BB*HEADS*2*4;      // 32*4*2 f32
constexpr size_t QSC_OFF  = KSN_OFF  + (size_t)BB*KVH*2*4;        // 32*12 f32
constexpr size_t KSC_OFF  = QSC_OFF  + (size_t)BB*HEADS*4;        // 32*4 f32
constexpr size_t DYN_OFF  = KSC_OFF  + (size_t)BB*KVH*4;          // chunked scratch

static int pick_gn(int nb) {
    for (int g = 12; g >= 2; --g) if (nb % g == 0) return g;
    return 1;
}

extern "C" void kernel_launch(void* const* d_in, const int* in_sizes, int n_in,
                              void* d_out, int out_size, void* d_ws, size_t ws_size,
                              hipStream_t stream) {
    (void)in_sizes; (void)n_in; (void)out_size;

    const float* x       = (const float*)d_in[0];
    const float* cvec    = (const float*)d_in[1];
    const float* wq_w    = (const float*)d_in[2];
    const float* wq_b    = (const float*)d_in[3];
    const float* wkv_w   = (const float*)d_in[4];
    const float* wkv_b   = (const float*)d_in[5];
    const float* dwc_w   = (const float*)d_in[6];
    const float* dwc_b   = (const float*)d_in[7];
    const float* proj_w  = (const float*)d_in[8];
    const float* proj_b  = (const float*)d_in[9];
    const float* adaln_w = (const float*)d_in[10];
    const float* adaln_b = (const float*)d_in[11];
    const float* mlp_w1  = (const float*)d_in[12];
    const float* mlp_b1  = (const float*)d_in[13];
    const float* mlp_w2  = (const float*)d_in[14];
    const float* mlp_b2  = (const float*)d_in[15];

    // ---- adaptive chunk size: largest CB batches whose scratch fits ws_size ----
    int CB = 0;
    for (int cb = 32; cb >= 1; cb >>= 1) {
        size_t rows = (size_t)cb * 1024;
        size_t attn = rows * (1152*2 /*XM*/ + 1152*2 /*QL*/ + 768*2 /*KVL*/ + 384*2 /*VD*/ + 1152*2 /*OB*/)
                    + (size_t)cb * (4*8*9216*4 /*KVMp*/ + 4*9216*4 /*KVM*/);
        size_t mlp  = rows * (1152*2 + 4608*2);
        size_t need = DYN_OFF + (attn > mlp ? attn : mlp);
        if (need <= ws_size) { CB = cb; break; }
    }
    if (CB == 0) return;
    const size_t CROWS = (size_t)CB * 1024;

    char* ws = (char*)d_ws;
    unsigned short* WQKV = (unsigned short*)(ws + WQKV_OFF);
    unsigned short* WPT  = (unsigned short*)(ws + WPT_OFF);
    unsigned short* W1T  = (unsigned short*)(ws + W1T_OFF);
    unsigned short* W2T  = (unsigned short*)(ws + W2T_OFF);
    float*          MODp = (float*)(ws + MOD_OFF);
    float*          QSN  = (float*)(ws + QSN_OFF);
    float*          KSN  = (float*)(ws + KSN_OFF);
    float*          QSC  = (float*)(ws + QSC_OFF);
    float*          KSC  = (float*)(ws + KSC_OFF);
    char* dyn = ws + DYN_OFF;
    unsigned short* XMc  = (unsigned short*)dyn;
    unsigned short* QLc  = (unsigned short*)(dyn + CROWS * 1152 * 2);
    unsigned short* KVLc = (unsigned short*)((char*)QLc + CROWS * 1152 * 2);
    float*          KVMp = (float*)((char*)KVLc + CROWS * 768 * 2);
    float*          KVMc = (float*)((char*)KVMp + (size_t)CB * 4 * 8 * 9216 * 4);
    unsigned short* VDc  = (unsigned short*)((char*)KVMc + (size_t)CB * 4 * 9216 * 4);
    unsigned short* OBc  = (unsigned short*)((char*)VDc + CROWS * 384 * 2);
    unsigned short* XM2  = (unsigned short*)dyn;
    unsigned short* Hc   = (unsigned short*)(dyn + CROWS * 1152 * 2);
    float*          OUT  = (float*)d_out;

    dim3 tb(32, 8);
    k_transpose_bf16<<<dim3(36, 36),  tb, 0, stream>>>(wq_w,   WQKV,             1152, 1152);
    k_transpose_bf16<<<dim3(36, 24),  tb, 0, stream>>>(wkv_w,  WQKV + 1152*1152, 1152, 768);
    k_transpose_bf16<<<dim3(36, 36),  tb, 0, stream>>>(proj_w, WPT,              1152, 1152);
    k_transpose_bf16<<<dim3(36, 144), tb, 0, stream>>>(mlp_w1, W1T,              1152, 4608);
    k_transpose_bf16<<<dim3(144, 36), tb, 0, stream>>>(mlp_w2, W2T,              4608, 1152);

    k_mod<<<dim3(27, 4), 256, 0, stream>>>(cvec, adaln_w, adaln_b, MODp);
    hipMemsetAsync(ws + QSN_OFF, 0, (size_t)(BB*HEADS*2 + BB*KVH*2) * 4, stream);

    const int MB = (int)(CROWS >> 7);      // 128-row M blocks per chunk
    const int GM = MB < 16 ? MB : 16;
    const int GN_QKV  = pick_gn(15);       // 5
    const int GN_PROJ = pick_gn(9);        // 9
    const int GN_MLP1 = pick_gn(36);       // 12
    const int GN_MLP2 = pick_gn(9);        // 9

    // --- attention branch, chunked over batches ---
    for (int b0 = 0; b0 < BB; b0 += CB) {
        const int r0 = b0 << 10;
        const float* xch = x + (size_t)r0 * HID;
        k_ln_mod<<<(int)CROWS, 256, 0, stream>>>(xch, MODp, 0, 1, XMc, r0);
        k_gemm_bt<3><<<15 * MB, 256, 0, stream>>>(XMc, WQKV, wq_b, wkv_b, QLc, KVLc,
                                                  nullptr, nullptr, QSN, KSN,
                                                  0, 1152, r0, MB, GM, GN_QKV);
        k_dwconv<<<(int)(CROWS * 96 / 256), 256, 0, stream>>>(KVLc, dwc_w, dwc_b, VDc);
        k_kvpart<<<CB * 4 * 8, 256, 0, stream>>>(KVLc, KVMp);
        k_fin<<<1, 512, 0, stream>>>(QSN, KSN, QSC, KSC);
        k_kvred<<<CB * 144, 256, 0, stream>>>(KVMp, KSC, KVMc, b0);
        k_ogemm<<<dim3(8, HEADS, CB), 256, 0, stream>>>(QLc, QSC, KVMc, VDc, OBc, b0);
        k_gemm_bt<2><<<9 * MB, 256, 0, stream>>>(OBc, WPT, proj_b, nullptr, OUT + (size_t)r0 * HID, nullptr,
                                                 xch, MODp + 2 * HID, nullptr, nullptr,
                                                 1152, 1152, r0, MB, GM, GN_PROJ);
    }

    // --- MLP branch, chunked over rows (d_out now holds x1 = x + gate*attn) ---
    for (int r0 = 0; r0 < ROWS; r0 += (int)CROWS) {
        float* x1ch = OUT + (size_t)r0 * HID;
        k_ln_mod<<<(int)CROWS, 256, 0, stream>>>(x1ch, MODp, 3, 4, XM2, r0);
        k_gemm_bt<1><<<36 * MB, 256, 0, stream>>>(XM2, W1T, mlp_b1, nullptr, Hc, nullptr,
                                                  nullptr, nullptr, nullptr, nullptr,
                                                  4608, 1152, 0, MB, GM, GN_MLP1);
        k_gemm_bt<2><<<9 * MB, 256, 0, stream>>>(Hc, W2T, mlp_b2, nullptr, x1ch, nullptr,
                                                 x1ch, MODp + 5 * HID, nullptr, nullptr,
                                                 1152, 4608, r0, MB, GM, GN_MLP2);
    }
}

// Round 8
// 1887.971 us; speedup vs baseline: 1.9731x; 1.0565x over previous
//
#include <hip/hip_runtime.h>
#include <hip/hip_bf16.h>
#include <cstdint>
#include <cstddef>

#define DEV __device__ __forceinline__

// ---------------- problem constants ----------------
constexpr int BB    = 32;
constexpr int SEQ   = 1024;
constexpr int HID   = 1152;
constexpr int HEADS = 12;
constexpr int KVH   = 4;
constexpr int HD    = 96;
constexpr int KVC   = 384;   // KVH*HD
constexpr int MLPD  = 4608;
constexpr int ROWS  = BB * SEQ;          // 32768
constexpr int MODW  = 6 * HID;           // 6912

typedef __attribute__((ext_vector_type(8))) short short8;
typedef __attribute__((ext_vector_type(4))) float f32x4;

// ---------------- helpers ----------------
DEV float bfu2f(unsigned short u) {
    unsigned v = ((unsigned)u) << 16;
    return __builtin_bit_cast(float, v);
}
DEV unsigned short f2bf16u(float f) {
    unsigned u = __builtin_bit_cast(unsigned, f);
    u += 0x7FFFu + ((u >> 16) & 1u);   // RNE
    return (unsigned short)(u >> 16);
}
DEV unsigned pack2(float a, float b) {
    return (unsigned)f2bf16u(a) | ((unsigned)f2bf16u(b) << 16);
}
DEV float gelu_tanh(float x) {
    float x3 = x * x * x;
    float t = tanhf(0.7978845608028654f * (x + 0.044715f * x3));
    return 0.5f * x * (1.f + t);
}

// async global->LDS, 16B per lane. LDS dest must be wave-uniform base (+lane*16).
DEV void gload16(const void* g, void* l) {
    __builtin_amdgcn_global_load_lds(
        (const __attribute__((address_space(1))) unsigned int*)g,
        (__attribute__((address_space(3))) unsigned int*)l,
        16, 0, 0);
}

// block reduce of two floats, blockDim.x == 256
DEV void block_reduce2(float& a, float& b) {
    #pragma unroll
    for (int off = 32; off > 0; off >>= 1) {
        a += __shfl_down(a, off, 64);
        b += __shfl_down(b, off, 64);
    }
    __shared__ float sa[4], sb[4];
    int w = threadIdx.x >> 6;
    if ((threadIdx.x & 63) == 0) { sa[w] = a; sb[w] = b; }
    __syncthreads();
    a = sa[0] + sa[1] + sa[2] + sa[3];
    b = sb[0] + sb[1] + sb[2] + sb[3];
    __syncthreads();
}

// ---------------- weight transpose + bf16 convert ----------------
__global__ void k_transpose_bf16(const float* __restrict__ in,
                                 unsigned short* __restrict__ out, int K, int N) {
    __shared__ float tile[32][33];
    int kb = blockIdx.x * 32;
    int nb = blockIdx.y * 32;
    int tx = threadIdx.x, ty = threadIdx.y;   // (32, 8)
    #pragma unroll
    for (int j = 0; j < 4; j++) {
        int k = kb + ty + j * 8;
        tile[ty + j * 8][tx] = (k < K && nb + tx < N) ? in[(size_t)k * N + nb + tx] : 0.f;
    }
    __syncthreads();
    #pragma unroll
    for (int j = 0; j < 4; j++) {
        int n = nb + ty + j * 8;
        if (n < N && kb + tx < K)
            out[(size_t)n * K + kb + tx] = f2bf16u(tile[tx][ty + j * 8]);
    }
}

// ---------------- adaLN: mod = silu(c) @ adaln_w + adaln_b ----------------
__global__ __launch_bounds__(256) void k_mod(const float* __restrict__ cvec,
                                             const float* __restrict__ w,
                                             const float* __restrict__ bias,
                                             float* __restrict__ mod) {
    const int col = blockIdx.x * 256 + threadIdx.x;
    const int bg = blockIdx.y * 8;
    __shared__ float sc[8][HID];
    for (int t = threadIdx.x; t < 8 * HID; t += 256) {
        int bb = t / HID, k = t % HID;
        float v = cvec[(bg + bb) * HID + k];
        sc[bb][k] = v / (1.f + __expf(-v));
    }
    __syncthreads();
    float acc[8];
    const float bv = bias[col];
    #pragma unroll
    for (int b = 0; b < 8; b++) acc[b] = bv;
    for (int k = 0; k < HID; k++) {
        float wv = w[(size_t)k * MODW + col];
        #pragma unroll
        for (int b = 0; b < 8; b++) acc[b] += sc[b][k] * wv;
    }
    #pragma unroll
    for (int b = 0; b < 8; b++) mod[(size_t)(bg + b) * MODW + col] = acc[b];
}

// ---------------- layernorm + modulate -> bf16 ----------------
__global__ __launch_bounds__(256) void k_ln_mod(const float* __restrict__ x,
                                                const float* __restrict__ mod,
                                                int shift_chunk, int scale_chunk,
                                                unsigned short* __restrict__ out,
                                                int r0) {
    const size_t row = blockIdx.x;
    const int b = (int)((r0 + row) >> 10);
    const float4* xr = (const float4*)(x + row * HID);
    const int t = threadIdx.x;
    float4 v0 = xr[t];
    float4 v1 = make_float4(0.f, 0.f, 0.f, 0.f);
    if (t < 32) v1 = xr[256 + t];
    float s  = v0.x + v0.y + v0.z + v0.w + v1.x + v1.y + v1.z + v1.w;
    float s2 = v0.x*v0.x + v0.y*v0.y + v0.z*v0.z + v0.w*v0.w
             + v1.x*v1.x + v1.y*v1.y + v1.z*v1.z + v1.w*v1.w;
    block_reduce2(s, s2);
    const float mean = s * (1.f / HID);
    float var = s2 * (1.f / HID) - mean * mean;
    const float rstd = rsqrtf(fmaxf(var, 0.f) + 1e-6f);
    const float* shiftp = mod + (size_t)b * MODW + shift_chunk * HID;
    const float* scalep = mod + (size_t)b * MODW + scale_chunk * HID;
    {
        float4 sc = *(const float4*)(scalep + 4 * t);
        float4 sh = *(const float4*)(shiftp + 4 * t);
        float y0 = ((v0.x - mean) * rstd) * (1.f + sc.x) + sh.x;
        float y1 = ((v0.y - mean) * rstd) * (1.f + sc.y) + sh.y;
        float y2 = ((v0.z - mean) * rstd) * (1.f + sc.z) + sh.z;
        float y3 = ((v0.w - mean) * rstd) * (1.f + sc.w) + sh.w;
        uint2 o; o.x = pack2(y0, y1); o.y = pack2(y2, y3);
        *(uint2*)(out + row * HID + 4 * t) = o;
    }
    if (t < 32) {
        int col = 1024 + 4 * t;
        float4 sc = *(const float4*)(scalep + col);
        float4 sh = *(const float4*)(shiftp + col);
        float y0 = ((v1.x - mean) * rstd) * (1.f + sc.x) + sh.x;
        float y1 = ((v1.y - mean) * rstd) * (1.f + sc.y) + sh.y;
        float y2 = ((v1.z - mean) * rstd) * (1.f + sc.z) + sh.z;
        float y3 = ((v1.w - mean) * rstd) * (1.f + sc.w) + sh.w;
        uint2 o; o.x = pack2(y0, y1); o.y = pack2(y2, y3);
        *(uint2*)(out + row * HID + col) = o;
    }
}

// ---------------- bf16 MFMA GEMM: C = A(M,K) * BT(N,K)^T + bias ----------------
// 128x128 tile, BK=64, global_load_lds staging, source-swizzled LDS (0 bank conflicts).
// Supertile (GM x GN) + 2D per-XCD sub-tiles (XMg x XNg XCD grid): each XCD owns a
// (GM/XMg)m x (GN/XNg)n block group -> small retained B-slice in its private L2.
// __launch_bounds__(256,4): 64 VGPR + 64 AGPR = 128/wave exactly; (256,5) SPILLS (r4).
// EPI 1: out bf16 = gelu(acc + bias), NON-TEMPORAL store (H is write-once/read-once;
//        keeps A/B panels L3-resident).
// EPI 2: out fp32 = resid + gate[b,col]*(acc + bias)
// EPI 3: qkv split + fused focused-norm sums.
template <int EPI>
__global__ __launch_bounds__(256, 4) void k_gemm_bt(
        const unsigned short* __restrict__ A, const unsigned short* __restrict__ BT,
        const float* __restrict__ bias, const float* __restrict__ bias2,
        void* __restrict__ outp, void* __restrict__ out2,
        const float* __restrict__ resid, const float* __restrict__ gate,
        float* __restrict__ qsn, float* __restrict__ ksn,
        int Np, int K, int r0, int MBk, int GM, int GN, int XMg, int XNg) {
    __shared__ __align__(16) char As[16384];
    __shared__ __align__(16) char Bs[16384];
    __shared__ float sb2[16], sb6[16];
    const int tid  = threadIdx.x;
    const int lane = tid & 63;
    const int wave = tid >> 6;
    const int wr = wave >> 1, wc = wave & 1;

    // ---- supertile + 2D XCD sub-tile mapping (bijective; consecutive rr -> XCD rr&7) ----
    const int P  = GM * GN;
    const int s  = blockIdx.x / P;
    const int rr = blockIdx.x % P;
    const int xcd = rr & 7, off = rr >> 3;
    const int gm = GM / XMg, gn = GN / XNg;
    const int xm = xcd / XNg, xn = xcd % XNg;
    const int mloc = xm * gm + off / gn;
    const int nloc = xn * gn + off % gn;
    const int smCount = MBk / GM;
    const int sm = s % smCount, sn = s / smCount;
    const int m0 = (sm * GM + mloc) << 7;
    const int n0 = (sn * GN + nloc) << 7;

    // staging: wave w covers rows 32w..32w+31 (4 chunks of 8 rows = 1KB each).
    const int srow = lane >> 3;                 // 0..7
    const int kgrp = (lane & 7) ^ srow;         // swizzled k-group for this lane
    const unsigned short* aS = A  + (size_t)(m0 + 32 * wave + srow) * K + kgrp * 8;
    const unsigned short* bS = BT + (size_t)(n0 + 32 * wave + srow) * K + kgrp * 8;
    const size_t chunkK = (size_t)8 * K;        // 8 rows per chunk
    char* aD = As + wave * 4096;
    char* bD = Bs + wave * 4096;

    // fragment read offsets: byte = r*128 + ((kg ^ (r&7))<<4); kk=1 -> ^64
    const int hi = lane >> 4;
    const int lo = lane & 15;
    const int swz = ((hi ^ (lo & 7)) << 4);
    int aoff[4], boff[4];
    #pragma unroll
    for (int i = 0; i < 4; i++) {
        aoff[i] = (wr * 64 + i * 16 + lo) * 128 + swz;
        boff[i] = (wc * 64 + i * 16 + lo) * 128 + swz;
    }

    f32x4 acc[4][4];
    #pragma unroll
    for (int i = 0; i < 4; i++)
        #pragma unroll
        for (int j = 0; j < 4; j++)
            acc[i][j] = (f32x4){0.f, 0.f, 0.f, 0.f};

    if constexpr (EPI == 3) {
        if (tid < 16) { sb2[tid] = 0.f; sb6[tid] = 0.f; }
    }

    const int nk = K >> 6;
    for (int kt = 0; kt < nk; ++kt) {
        __syncthreads();
        #pragma unroll
        for (int j = 0; j < 4; j++) {
            gload16(aS + j * chunkK, aD + j * 1024);
            gload16(bS + j * chunkK, bD + j * 1024);
        }
        aS += 64; bS += 64;
        __syncthreads();
        #pragma unroll
        for (int kk = 0; kk < 2; kk++) {
            const int kx = kk << 6;
            short8 bfr[4];
            #pragma unroll
            for (int j = 0; j < 4; j++)
                bfr[j] = *(const short8*)(Bs + (boff[j] ^ kx));
            #pragma unroll
            for (int i = 0; i < 4; i++) {
                short8 af = *(const short8*)(As + (aoff[i] ^ kx));
                #pragma unroll
                for (int j = 0; j < 4; j++)
                    acc[i][j] = __builtin_amdgcn_mfma_f32_16x16x32_bf16(af, bfr[j], acc[i][j], 0, 0, 0);
            }
        }
    }

    // epilogue. C/D layout: col = lane&15, row = 4*(lane>>4)+reg
    const int c_l = lane & 15;
    const int r_l = (lane >> 4) << 2;
    #pragma unroll
    for (int j = 0; j < 4; j++) {
        const int fcol = n0 + wc * 64 + j * 16 + c_l;
        float bvv;
        if constexpr (EPI == 3) bvv = (fcol < HID) ? bias[fcol] : bias2[fcol - HID];
        else                    bvv = bias[fcol];
        float s2l = 0.f, s6l = 0.f;
        #pragma unroll
        for (int i = 0; i < 4; i++) {
            const int frow = m0 + wr * 64 + i * 16 + r_l;
            #pragma unroll
            for (int r = 0; r < 4; r++) {
                float v = acc[i][j][r] + bvv;
                if constexpr (EPI == 1) {
                    __builtin_nontemporal_store(f2bf16u(gelu_tanh(v)),
                        (unsigned short*)outp + (size_t)(frow + r) * Np + fcol);
                } else if constexpr (EPI == 2) {
                    const size_t off2 = (size_t)(frow + r) * Np + fcol;
                    const int bb = (r0 + frow + r) >> 10;
                    ((float*)outp)[off2] = resid[off2] + gate[(size_t)bb * MODW + fcol] * v;
                } else {  // EPI 3
                    unsigned short bf = f2bf16u(v);
                    if (fcol < HID) ((unsigned short*)outp)[(size_t)(frow + r) * HID + fcol] = bf;
                    else            ((unsigned short*)out2)[(size_t)(frow + r) * (2*KVC) + (fcol - HID)] = bf;
                    if (fcol < HID + KVC) {
                        float rv = fmaxf(v, 0.f);
                        float v2 = rv * rv;
                        s2l += v2;
                        s6l += v2 * v2 * v2;
                    }
                }
            }
        }
        if constexpr (EPI == 3) {
            if (fcol < HID + KVC) {
                s2l += __shfl_down(s2l, 32, 64); s2l += __shfl_down(s2l, 16, 64);
                s6l += __shfl_down(s6l, 32, 64); s6l += __shfl_down(s6l, 16, 64);
                if (lane < 16) {
                    const int slot = (fcol < HID) ? (fcol / 96) : (12 + (fcol - HID) / 96);
                    atomicAdd(&sb2[slot], s2l);
                    atomicAdd(&sb6[slot], s6l);
                }
            }
        }
    }
    if constexpr (EPI == 3) {
        __syncthreads();
        if (tid < 16) {
            const int b = (r0 + m0) >> 10;
            if (tid < 12) {
                atomicAdd(&qsn[(b * HEADS + tid) * 2],     sb2[tid]);
                atomicAdd(&qsn[(b * HEADS + tid) * 2 + 1], sb6[tid]);
            } else {
                atomicAdd(&ksn[(b * KVH + tid - 12) * 2],     sb2[tid]);
                atomicAdd(&ksn[(b * KVH + tid - 12) * 2 + 1], sb6[tid]);
            }
        }
    }
}

// ---------------- finisher: norm sums -> scales (1 block, 512 threads) ----------------
__global__ void k_fin(const float* __restrict__ qsn, const float* __restrict__ ksn,
                      float* __restrict__ qsc, float* __restrict__ ksc) {
    const int t = threadIdx.x;
    if (t < BB * HEADS) {
        float s2 = qsn[t * 2], s6 = qsn[t * 2 + 1];
        float apn = (s6 == 0.f) ? 1e-12f : sqrtf(s6);
        qsc[t] = sqrtf(s2) / apn;
    } else if (t < BB * HEADS + BB * KVH) {
        int i = t - BB * HEADS;
        float s2 = ksn[i * 2], s6 = ksn[i * 2 + 1];
        float apn = (s6 == 0.f) ? 1e-12f : sqrtf(s6);
        ksc[i] = sqrtf(s2) / apn;
    }
}

// ---------------- depthwise 3x3 conv (bf16 in): 4 channels/thread ----------------
__global__ __launch_bounds__(256) void k_dwconv(const unsigned short* __restrict__ kvl,
                                                const float* __restrict__ w,
                                                const float* __restrict__ bias,
                                                unsigned short* __restrict__ vd) {
    const int idx = blockIdx.x * 256 + threadIdx.x;   // < CROWS*96
    const int c4 = idx % 96;
    const int bn = idx / 96;
    const int n = bn & 1023;
    const int b = bn >> 10;
    const int y = n >> 5, xx = n & 31;
    float4 acc = *(const float4*)(bias + c4 * 4);
    #pragma unroll
    for (int dy = -1; dy <= 1; dy++) {
        const int yy = y + dy;
        if ((unsigned)yy > 31u) continue;
        #pragma unroll
        for (int dx = -1; dx <= 1; dx++) {
            const int xc = xx + dx;
            if ((unsigned)xc > 31u) continue;
            uint2 u = *(const uint2*)(kvl + ((size_t)b * SEQ + yy * 32 + xc) * (2*KVC) + KVC + c4 * 4);
            const int t = (dy + 1) * 3 + (dx + 1);
            acc.x += w[(c4 * 4 + 0) * 9 + t] * bfu2f((unsigned short)(u.x & 0xffff));
            acc.y += w[(c4 * 4 + 1) * 9 + t] * bfu2f((unsigned short)(u.x >> 16));
            acc.z += w[(c4 * 4 + 2) * 9 + t] * bfu2f((unsigned short)(u.y & 0xffff));
            acc.w += w[(c4 * 4 + 3) * 9 + t] * bfu2f((unsigned short)(u.y >> 16));
        }
    }
    uint2 o; o.x = pack2(acc.x, acc.y); o.y = pack2(acc.z, acc.w);
    *(uint2*)(vd + (size_t)idx * 4) = o;
}

// ---------------- kvmat partials: relu(k)^3 ^T @ v over 128-row chunk ----------------
__global__ __launch_bounds__(256) void k_kvpart(const unsigned short* __restrict__ kvl,
                                                float* __restrict__ kvmp) {
    const int chunk = blockIdx.x & 7;
    const int bh = blockIdx.x >> 3;
    const int b = bh >> 2, h = bh & 3;
    __shared__ float Ks[16][96], Vs[16][96];
    float acc[6][6];
    #pragma unroll
    for (int i = 0; i < 6; i++)
        #pragma unroll
        for (int j = 0; j < 6; j++) acc[i][j] = 0.f;
    const int ti = threadIdx.x >> 4, tj = threadIdx.x & 15;
    const unsigned short* kbase = kvl + ((size_t)b * SEQ + chunk * 128) * (2*KVC) + h * HD;
    for (int n0 = 0; n0 < 128; n0 += 16) {
        __syncthreads();
        // vectorized staging: 384 uint4 pieces (k: 0..191, v: 192..383)
        for (int i = threadIdx.x; i < 384; i += 256) {
            const int kv = (i >= 192);
            const int j = i - kv * 192;
            const int row = j / 12, c = j % 12;
            uint4 u = *(const uint4*)(kbase + (size_t)(n0 + row) * (2*KVC) + kv * KVC + c * 8);
            const unsigned short* e = (const unsigned short*)&u;
            if (!kv) {
                #pragma unroll
                for (int q = 0; q < 8; q++) {
                    float r = fmaxf(bfu2f(e[q]), 0.f);
                    Ks[row][c * 8 + q] = r * r * r;
                }
            } else {
                #pragma unroll
                for (int q = 0; q < 8; q++) Vs[row][c * 8 + q] = bfu2f(e[q]);
            }
        }
        __syncthreads();
        for (int nn = 0; nn < 16; nn++) {
            float av[6], bv[6];
            #pragma unroll
            for (int i = 0; i < 6; i++) av[i] = Ks[nn][ti * 6 + i];
            #pragma unroll
            for (int j = 0; j < 6; j++) bv[j] = Vs[nn][tj * 6 + j];
            #pragma unroll
            for (int i = 0; i < 6; i++)
                #pragma unroll
                for (int j = 0; j < 6; j++) acc[i][j] += av[i] * bv[j];
        }
    }
    float* out = kvmp + ((size_t)bh * 8 + chunk) * 9216;
    #pragma unroll
    for (int i = 0; i < 6; i++)
        #pragma unroll
        for (int j = 0; j < 6; j++)
            out[(size_t)(ti * 6 + i) * 96 + tj * 6 + j] = acc[i][j];
}

// ---------------- kvmat reduce: sum 8 partials, apply kscale, emit TRANSPOSED bf16 ----------------
// kvmT[bh][e][d] = bf16( ksc * sum_c kvmp[bh][c][d][e] )  -- B-operand layout for MFMA ogemm
__global__ __launch_bounds__(256) void k_kvred(const float* __restrict__ kvmp,
                                               const float* __restrict__ ksc,
                                               unsigned short* __restrict__ kvmT, int b0) {
    const int idx = blockIdx.x * 256 + threadIdx.x;   // < CB*4*9216
    const int bh = idx / 9216;
    const int i  = idx % 9216;                        // i = d*96 + e
    float s = 0.f;
    #pragma unroll
    for (int c = 0; c < 8; c++) s += kvmp[((size_t)bh * 8 + c) * 9216 + i];
    s *= ksc[(b0 + (bh >> 2)) * KVH + (bh & 3)];
    const int d = i / 96, e = i % 96;
    kvmT[(size_t)bh * 9216 + e * 96 + d] = f2bf16u(s);
}

// ---------------- o = focused(q) @ kvmat[h%4] + vd[h%4] -- MFMA version ----------------
// Block: 256 thr / 4 waves; 128 rows x 96 cols for one (b,h). q cubed into LDS (bf16,
// padded stride 104 -> 2-way banks = free); kvmT staged as B-operand (same proven BT
// fragment pattern as k_gemm_bt). K=96 = 3 MFMA k-steps.
__global__ __launch_bounds__(256) void k_ogemm(const unsigned short* __restrict__ ql,
                                               const float* __restrict__ qscale,
                                               const unsigned short* __restrict__ kvmT,
                                               const unsigned short* __restrict__ vd,
                                               unsigned short* __restrict__ obuf,
                                               int b0) {
    const int rc = blockIdx.x;   // 0..7 row chunks of 128
    const int h  = blockIdx.y;   // 0..11
    const int b  = blockIdx.z;   // local batch
    const int kvh = h & 3;
    __shared__ unsigned short Qs[128][104];
    __shared__ unsigned short Ms[96][104];
    const int tid = threadIdx.x;
    const float qs = qscale[(b0 + b) * HEADS + h];
    // stage Ms (96x96 bf16, already transposed by k_kvred): 1152 uint4
    const unsigned short* mt = kvmT + (size_t)(b * KVH + kvh) * 9216;
    for (int i = tid; i < 1152; i += 256) {
        const int row = i / 12, c = i % 12;
        *(uint4*)&Ms[row][c * 8] = *(const uint4*)(mt + row * 96 + c * 8);
    }
    // stage Qs = bf16( qs * relu(q)^3 ): 1536 uint4
    const unsigned short* qb = ql + ((size_t)(b * SEQ + rc * 128)) * HID + h * HD;
    for (int i = tid; i < 1536; i += 256) {
        const int row = i / 12, c = i % 12;
        uint4 u = *(const uint4*)(qb + (size_t)row * HID + c * 8);
        const unsigned short* e = (const unsigned short*)&u;
        unsigned short o8[8];
        #pragma unroll
        for (int q = 0; q < 8; q++) {
            float a = fmaxf(bfu2f(e[q]), 0.f);
            o8[q] = f2bf16u(qs * a * a * a);
        }
        *(uint4*)&Qs[row][c * 8] = *(uint4*)o8;
    }
    __syncthreads();
    const int wave = tid >> 6, lane = tid & 63;
    const int lo = lane & 15, hi = lane >> 4;
    f32x4 acc[2][6];
    #pragma unroll
    for (int m = 0; m < 2; m++)
        #pragma unroll
        for (int n = 0; n < 6; n++) acc[m][n] = (f32x4){0.f, 0.f, 0.f, 0.f};
    #pragma unroll
    for (int ks = 0; ks < 3; ks++) {
        short8 af[2], bf[6];
        #pragma unroll
        for (int m = 0; m < 2; m++)
            af[m] = *(const short8*)&Qs[wave * 32 + m * 16 + lo][ks * 32 + 8 * hi];
        #pragma unroll
        for (int n = 0; n < 6; n++)
            bf[n] = *(const short8*)&Ms[n * 16 + lo][ks * 32 + 8 * hi];
        #pragma unroll
        for (int m = 0; m < 2; m++)
            #pragma unroll
            for (int n = 0; n < 6; n++)
                acc[m][n] = __builtin_amdgcn_mfma_f32_16x16x32_bf16(af[m], bf[n], acc[m][n], 0, 0, 0);
    }
    // epilogue: C/D col = lane&15 (-> e), row = 4*(lane>>4)+r (-> seq row)
    #pragma unroll
    for (int m = 0; m < 2; m++) {
        #pragma unroll
        for (int n = 0; n < 6; n++) {
            const int e = n * 16 + lo;
            #pragma unroll
            for (int r = 0; r < 4; r++) {
                const size_t gr = (size_t)b * SEQ + rc * 128 + wave * 32 + m * 16 + 4 * hi + r;
                float v = acc[m][n][r] + bfu2f(vd[gr * KVC + kvh * HD + e]);
                obuf[gr * HID + h * HD + e] = f2bf16u(v);
            }
        }
    }
}

// ---------------- fixed workspace layout ----------------
constexpr size_t WQKV_OFF = 0;                                    // [1920][1152] bf16
constexpr size_t WPT_OFF  = WQKV_OFF + (size_t)1920*1152*2;       // [1152][1152] bf16
constexpr size_t W1T_OFF  = WPT_OFF  + (size_t)1152*1152*2;       // [4608][1152] bf16
constexpr size_t W2T_OFF  = W1T_OFF  + (size_t)4608*1152*2;       // [1152][4608] bf16
constexpr size_t MOD_OFF  = W2T_OFF  + (size_t)1152*4608*2;       // 32*6912 f32
constexpr size_t QSN_OFF  = MOD_OFF  + (size_t)BB*MODW*4;         // 32*12*2 f32 (s2,s6)
constexpr size_t KSN_OFF  = QSN_OFF  + (size_t)BB*HEADS*2*4;      // 32*4*2 f32
constexpr size_t QSC_OFF  = KSN_OFF  + (size_t)BB*KVH*2*4;        // 32*12 f32
constexpr size_t KSC_OFF  = QSC_OFF  + (size_t)BB*HEADS*4;        // 32*4 f32
constexpr size_t DYN_OFF  = KSC_OFF  + (size_t)BB*KVH*4;          // chunked scratch

extern "C" void kernel_launch(void* const* d_in, const int* in_sizes, int n_in,
                              void* d_out, int out_size, void* d_ws, size_t ws_size,
                              hipStream_t stream) {
    (void)in_sizes; (void)n_in; (void)out_size;

    const float* x       = (const float*)d_in[0];
    const float* cvec    = (const float*)d_in[1];
    const float* wq_w    = (const float*)d_in[2];
    const float* wq_b    = (const float*)d_in[3];
    const float* wkv_w   = (const float*)d_in[4];
    const float* wkv_b   = (const float*)d_in[5];
    const float* dwc_w   = (const float*)d_in[6];
    const float* dwc_b   = (const float*)d_in[7];
    const float* proj_w  = (const float*)d_in[8];
    const float* proj_b  = (const float*)d_in[9];
    const float* adaln_w = (const float*)d_in[10];
    const float* adaln_b = (const float*)d_in[11];
    const float* mlp_w1  = (const float*)d_in[12];
    const float* mlp_b1  = (const float*)d_in[13];
    const float* mlp_w2  = (const float*)d_in[14];
    const float* mlp_b2  = (const float*)d_in[15];

    // ---- adaptive chunk size ----
    int CB = 0;
    for (int cb = 32; cb >= 1; cb >>= 1) {
        size_t rows = (size_t)cb * 1024;
        size_t attn = rows * (1152*2 + 1152*2 + 768*2 + 384*2 + 1152*2)
                    + (size_t)cb * (4*8*9216*4 /*KVMp*/ + 4*9216*2 /*KVMT*/);
        size_t mlp  = rows * (1152*2 + 4608*2);
        size_t need = DYN_OFF + (attn > mlp ? attn : mlp);
        if (need <= ws_size) { CB = cb; break; }
    }
    if (CB == 0) return;
    const size_t CROWS = (size_t)CB * 1024;

    char* ws = (char*)d_ws;
    unsigned short* WQKV = (unsigned short*)(ws + WQKV_OFF);
    unsigned short* WPT  = (unsigned short*)(ws + WPT_OFF);
    unsigned short* W1T  = (unsigned short*)(ws + W1T_OFF);
    unsigned short* W2T  = (unsigned short*)(ws + W2T_OFF);
    float*          MODp = (float*)(ws + MOD_OFF);
    float*          QSN  = (float*)(ws + QSN_OFF);
    float*          KSN  = (float*)(ws + KSN_OFF);
    float*          QSC  = (float*)(ws + QSC_OFF);
    float*          KSC  = (float*)(ws + KSC_OFF);
    char* dyn = ws + DYN_OFF;
    unsigned short* XMc  = (unsigned short*)dyn;
    unsigned short* QLc  = (unsigned short*)(dyn + CROWS * 1152 * 2);
    unsigned short* KVLc = (unsigned short*)((char*)QLc + CROWS * 1152 * 2);
    float*          KVMp = (float*)((char*)KVLc + CROWS * 768 * 2);
    unsigned short* KVMT = (unsigned short*)((char*)KVMp + (size_t)CB * 4 * 8 * 9216 * 4);
    unsigned short* VDc  = (unsigned short*)((char*)KVMT + (size_t)CB * 4 * 9216 * 2);
    unsigned short* OBc  = (unsigned short*)((char*)VDc + CROWS * 384 * 2);
    unsigned short* XM2  = (unsigned short*)dyn;
    unsigned short* Hc   = (unsigned short*)(dyn + CROWS * 1152 * 2);
    float*          OUT  = (float*)d_out;

    dim3 tb(32, 8);
    k_transpose_bf16<<<dim3(36, 36),  tb, 0, stream>>>(wq_w,   WQKV,             1152, 1152);
    k_transpose_bf16<<<dim3(36, 24),  tb, 0, stream>>>(wkv_w,  WQKV + 1152*1152, 1152, 768);
    k_transpose_bf16<<<dim3(36, 36),  tb, 0, stream>>>(proj_w, WPT,              1152, 1152);
    k_transpose_bf16<<<dim3(36, 144), tb, 0, stream>>>(mlp_w1, W1T,              1152, 4608);
    k_transpose_bf16<<<dim3(144, 36), tb, 0, stream>>>(mlp_w2, W2T,              4608, 1152);

    k_mod<<<dim3(27, 4), 256, 0, stream>>>(cvec, adaln_w, adaln_b, MODp);
    hipMemsetAsync(ws + QSN_OFF, 0, (size_t)(BB*HEADS*2 + BB*KVH*2) * 4, stream);

    const int MB = (int)(CROWS >> 7);      // 128-row M blocks per chunk
    const int GM = MB < 16 ? MB : 16;      // 8 or 16; both divisible by XMg used below

    // --- attention branch, chunked over batches ---
    for (int b0 = 0; b0 < BB; b0 += CB) {
        const int r0 = b0 << 10;
        const float* xch = x + (size_t)r0 * HID;
        k_ln_mod<<<(int)CROWS, 256, 0, stream>>>(xch, MODp, 0, 1, XMc, r0);
        // qkv: NB=15, GN=5 (sn=3), XCD grid 8x1 -> per-XCD 2m x 5n (B-slice 1.5MB)
        k_gemm_bt<3><<<15 * MB, 256, 0, stream>>>(XMc, WQKV, wq_b, wkv_b, QLc, KVLc,
                                                  nullptr, nullptr, QSN, KSN,
                                                  0, 1152, r0, MB, GM, 5, 8, 1);
        k_dwconv<<<(int)(CROWS * 96 / 256), 256, 0, stream>>>(KVLc, dwc_w, dwc_b, VDc);
        k_kvpart<<<CB * 4 * 8, 256, 0, stream>>>(KVLc, KVMp);
        k_fin<<<1, 512, 0, stream>>>(QSN, KSN, QSC, KSC);
        k_kvred<<<CB * 144, 256, 0, stream>>>(KVMp, KSC, KVMT, b0);
        k_ogemm<<<dim3(8, HEADS, CB), 256, 0, stream>>>(QLc, QSC, KVMT, VDc, OBc, b0);
        // proj: NB=9, GN=9 (sn=1, A once), XCD grid 8x1
        k_gemm_bt<2><<<9 * MB, 256, 0, stream>>>(OBc, WPT, proj_b, nullptr, OUT + (size_t)r0 * HID, nullptr,
                                                 xch, MODp + 2 * HID, nullptr, nullptr,
                                                 1152, 1152, r0, MB, GM, 9, 8, 1);
    }

    // --- MLP branch, chunked over rows (d_out now holds x1 = x + gate*attn) ---
    for (int r0 = 0; r0 < ROWS; r0 += (int)CROWS) {
        float* x1ch = OUT + (size_t)r0 * HID;
        k_ln_mod<<<(int)CROWS, 256, 0, stream>>>(x1ch, MODp, 3, 4, XM2, r0);
        // mlp1: NB=36, GN=12 (sn=3), XCD grid 2x4 -> per-XCD 8m x 3n (B-slice 0.9MB)
        k_gemm_bt<1><<<36 * MB, 256, 0, stream>>>(XM2, W1T, mlp_b1, nullptr, Hc, nullptr,
                                                  nullptr, nullptr, nullptr, nullptr,
                                                  4608, 1152, 0, MB, GM, 12, 2, 4);
        // mlp2: NB=9, GN=9 (sn=1, A once), XCD grid 8x1
        k_gemm_bt<2><<<9 * MB, 256, 0, stream>>>(Hc, W2T, mlp_b2, nullptr, x1ch, nullptr,
                                                 x1ch, MODp + 5 * HID, nullptr, nullptr,
                                                 1152, 4608, r0, MB, GM, 9, 8, 1);
    }
}